// Round 8
// baseline (1048.247 us; speedup 1.0000x reference)
//
#include <hip/hip_runtime.h>
#include <math.h>

#define D 128
#define NEG_SLOPE 0.2f
#define REG_LAMBDA 1e-4f
#define NORM_EPS 1e-12f

#define RPB 256          // rows per coarse bucket
#define RPB_SHIFT 8
#define MAXB 1024        // max coarse buckets (N <= 262144)
#define CHUNK 2048       // edges per bscatter block (33 KB LDS -> 4 blocks/CU)
#define TCSH 14          // 16384 cols per col-tile (for within-row edge ordering)
#define KEYMAX 4096      // 256 rows * Tc ; Tc<=16 -> N <= 262144

#define XPAD 264         // padded LDS row stride in bf16 elems (256 + 8)

using bf16x8 = __attribute__((ext_vector_type(8))) short;
using f32x4  = __attribute__((ext_vector_type(4))) float;
using f32x2  = __attribute__((ext_vector_type(2))) float;

__device__ __forceinline__ float wave_red(float v){
  #pragma unroll
  for (int o = 32; o > 0; o >>= 1) v += __shfl_xor(v, o, 64);
  return v;
}

__device__ __forceinline__ unsigned short f2bf(float f){
  unsigned int u = __float_as_uint(f);
  unsigned int r = (u + 0x7fffu + ((u >> 16) & 1u)) >> 16;  // RNE
  return (unsigned short)r;
}
__device__ __forceinline__ float bf_lo(unsigned int x){ return __uint_as_float(x << 16); }
__device__ __forceinline__ float bf_hi(unsigned int x){ return __uint_as_float(x & 0xffff0000u); }

// packed 2xf32 FMA (VOP3P): d = a*b + c on both halves
__device__ __forceinline__ f32x2 pk_fma(f32x2 a, f32x2 b, f32x2 c){
  f32x2 d;
  asm("v_pk_fma_f32 %0, %1, %2, %3" : "=v"(d) : "v"(a), "v"(b), "v"(c));
  return d;
}
// hardware 2xf32 -> packed bf16 (RNE)
__device__ __forceinline__ unsigned int pk_bf16(float lo, float hi){
  unsigned int d;
  asm("v_cvt_pk_bf16_f32 %0, %1, %2" : "=v"(d) : "v"(lo), "v"(hi));
  return d;
}

// fp32 pair -> (bf16 pair packed in uint, fp8-e4m3 pair packed in ushort)
__global__ __launch_bounds__(256) void toq_kernel(const float* __restrict__ src, unsigned int* __restrict__ dstb,
                                                  unsigned short* __restrict__ dst8, int npairs){
  int i = blockIdx.x*256 + threadIdx.x;
  if (i >= npairs) return;
  float2 v = ((const float2*)src)[i];
  dstb[i] = (unsigned int)f2bf(v.x) | ((unsigned int)f2bf(v.y) << 16);
  int p = __builtin_amdgcn_cvt_pk_fp8_f32(v.x, v.y, 0, false);
  dst8[i] = (unsigned short)(p & 0xffff);
}

// W_gcn/W_bi (fp32 row-major) -> per-layer MFMA B-fragment order bf16.
__global__ __launch_bounds__(256) void wconv_kernel(const float* __restrict__ Wg, const float* __restrict__ Wb,
                                                    unsigned short* __restrict__ Wf, int L){
  int idx = blockIdx.x*256 + threadIdx.x;
  int total = L * 256 * D;
  if (idx >= total) return;
  int l = idx >> 15;
  int rem = idx & 32767;
  int k = rem >> 7;
  int n = rem & 127;
  float v = (k < 128) ? Wg[((size_t)l*128 + k)*D + n] : Wb[((size_t)l*128 + (k-128))*D + n];
  int ks = k >> 5, quad = (k >> 3) & 3, j = k & 7;
  int t = n >> 4, ln = (quad << 4) | (n & 15);
  Wf[(size_t)l*32768 + (((ks*8 + t)*64 + ln)*8 + j)] = f2bf(v);
}

// K1: coarse bucket histogram, LDS-aggregated, loads batched 4-wide
__global__ __launch_bounds__(256) void bhist_kernel(const int* __restrict__ erow, int* __restrict__ bcnt, int nnz, int nbk){
  __shared__ int h[MAXB];
  for (int i = threadIdx.x; i < nbk; i += 256) h[i] = 0;
  __syncthreads();
  int stride = gridDim.x * 256;
  int e = blockIdx.x*256 + threadIdx.x;
  for (; e + 3*stride < nnz; e += 4*stride){
    int r0 = erow[e], r1 = erow[e+stride], r2 = erow[e+2*stride], r3 = erow[e+3*stride];
    atomicAdd(&h[r0 >> RPB_SHIFT], 1);
    atomicAdd(&h[r1 >> RPB_SHIFT], 1);
    atomicAdd(&h[r2 >> RPB_SHIFT], 1);
    atomicAdd(&h[r3 >> RPB_SHIFT], 1);
  }
  for (; e < nnz; e += stride)
    atomicAdd(&h[erow[e] >> RPB_SHIFT], 1);
  __syncthreads();
  for (int i = threadIdx.x; i < nbk; i += 256){
    int c = h[i];
    if (c) atomicAdd(&bcnt[i], c);
  }
}

// K2: exclusive scan of bucket counts (single block)
__global__ __launch_bounds__(1024) void bscan_kernel(const int* __restrict__ bcnt, int* __restrict__ bbase,
                                                     int* __restrict__ bcur, int* __restrict__ rowptr,
                                                     int nbk, int nnz, int n){
  __shared__ int tmp[1024];
  int t = threadIdx.x;
  int v = (t < nbk) ? bcnt[t] : 0;
  tmp[t] = v; __syncthreads();
  #pragma unroll
  for (int off = 1; off < 1024; off <<= 1){
    int a = (t >= off) ? tmp[t-off] : 0; __syncthreads();
    tmp[t] += a; __syncthreads();
  }
  if (t < nbk){ int b = tmp[t] - v; bbase[t] = b; bcur[t] = b; }
  if (t == 0){ bbase[nbk] = nnz; rowptr[n] = nnz; }
}

// K3: coarse scatter. Block sorts a CHUNK of edges by bucket in LDS, reserves
// global ranges, writes coalesced runs. ebuf.x = col | (row_low8 << 20).
__global__ __launch_bounds__(256) void bscatter_kernel(const int* __restrict__ erow, const int* __restrict__ ecol,
                                                       const float* __restrict__ eval, int* __restrict__ bcur,
                                                       int2* __restrict__ ebuf, int nnz, int nbk){
  __shared__ int2 ls[CHUNK];
  __shared__ int gdst[CHUNK];
  __shared__ int h[MAXB];
  __shared__ int hx[MAXB];
  __shared__ int tmp[256];
  int tid = threadIdx.x;
  int base = blockIdx.x * CHUNK;
  int cn = min(CHUNK, nnz - base);
  bool full = (cn == CHUNK);
  for (int i = tid; i < nbk; i += 256) h[i] = 0;
  __syncthreads();

  int r[8];
  if (full){
    #pragma unroll
    for (int k = 0; k < 8; k++) r[k] = erow[base + tid + 256*k];
    #pragma unroll
    for (int k = 0; k < 8; k++) atomicAdd(&h[r[k] >> RPB_SHIFT], 1);
  } else {
    #pragma unroll
    for (int k = 0; k < 8; k++){
      int i = tid + 256*k;
      r[k] = (i < cn) ? erow[base + i] : -1;
    }
    #pragma unroll
    for (int k = 0; k < 8; k++)
      if (r[k] >= 0) atomicAdd(&h[r[k] >> RPB_SHIFT], 1);
  }
  __syncthreads();

  int b0 = tid*4;
  int c0=0,c1=0,c2=0,c3=0;
  if (b0 < nbk){
    c0 = h[b0];
    if (b0+1 < nbk) c1 = h[b0+1];
    if (b0+2 < nbk) c2 = h[b0+2];
    if (b0+3 < nbk) c3 = h[b0+3];
  }
  int tsum = c0+c1+c2+c3;
  tmp[tid] = tsum; __syncthreads();
  #pragma unroll
  for (int off = 1; off < 256; off <<= 1){
    int a = (tid >= off) ? tmp[tid-off] : 0; __syncthreads();
    tmp[tid] += a; __syncthreads();
  }
  int tbase = tmp[tid] - tsum;
  if (b0 < nbk){
    hx[b0] = tbase;
    if (b0+1 < nbk) hx[b0+1] = tbase + c0;
    if (b0+2 < nbk) hx[b0+2] = tbase + c0 + c1;
    if (b0+3 < nbk) hx[b0+3] = tbase + c0 + c1 + c2;
  }
  __syncthreads();
  for (int i = tid; i < nbk; i += 256){
    int c = h[i];
    if (c > 0){
      int gb = atomicAdd(&bcur[i], c);
      h[i] = gb - hx[i];
    }
  }
  __syncthreads();

  if (full){
    int c[8]; float v[8];
    #pragma unroll
    for (int k = 0; k < 8; k++) c[k] = ecol[base + tid + 256*k];
    #pragma unroll
    for (int k = 0; k < 8; k++) v[k] = eval[base + tid + 256*k];
    #pragma unroll
    for (int k = 0; k < 8; k++){
      int rr = r[k];
      int b = rr >> RPB_SHIFT;
      int x = c[k] | ((rr & (RPB-1)) << 20);
      int lpos = atomicAdd(&hx[b], 1);
      ls[lpos] = make_int2(x, __float_as_int(v[k]));
      gdst[lpos] = h[b] + lpos;
    }
  } else {
    for (int i = tid; i < cn; i += 256){
      int rr = erow[base+i];
      int b = rr >> RPB_SHIFT;
      int x = ecol[base+i] | ((rr & (RPB-1)) << 20);
      int lpos = atomicAdd(&hx[b], 1);
      ls[lpos] = make_int2(x, __float_as_int(eval[base+i]));
      gdst[lpos] = h[b] + lpos;
    }
  }
  __syncthreads();
  if (full){
    #pragma unroll
    for (int k = 0; k < 8; k++){
      int i = tid + 256*k;
      ebuf[gdst[i]] = ls[i];
    }
  } else {
    for (int i = tid; i < cn; i += 256)
      ebuf[gdst[i]] = ls[i];
  }
}

// K4: one block per coarse bucket. Counting sort by key = (row_low8, col-tile)
// -> rowptr + final CSR (edges within a row ordered by col-tile).
// ep.x = byte offset into fp8 table (col * 128). Both passes batched 8-wide.
__global__ __launch_bounds__(256) void fscatter_kernel(const int2* __restrict__ ebuf, const int* __restrict__ bbase,
                                                       int2* __restrict__ ep, int* __restrict__ rowptr,
                                                       int Tc, int n){
  __shared__ int h[KEYMAX];
  __shared__ int tsum[256];
  int b = blockIdx.x;
  int tid = threadIdx.x;
  int s = bbase[b], e = bbase[b+1];
  int row0 = b << RPB_SHIFT;
  int nk = 256 * Tc;
  for (int i = tid; i < nk; i += 256) h[i] = 0;
  __syncthreads();

  int i = s + tid;
  for (; i + 256*7 < e; i += 256*8){
    int x[8];
    #pragma unroll
    for (int k = 0; k < 8; k++) x[k] = ebuf[i + 256*k].x;
    #pragma unroll
    for (int k = 0; k < 8; k++){
      int key = ((x[k] >> 20) & 255) * Tc + ((x[k] & 0xFFFFF) >> TCSH);
      atomicAdd(&h[key], 1);
    }
  }
  for (; i < e; i += 256){
    int x = ebuf[i].x;
    int key = ((x >> 20) & 255) * Tc + ((x & 0xFFFFF) >> TCSH);
    atomicAdd(&h[key], 1);
  }
  __syncthreads();
  // exclusive scan: thread tid owns keys of row tid (segment of Tc)
  int my0 = tid * Tc;
  int run = 0;
  for (int j = 0; j < Tc; j++){
    int c = h[my0 + j]; h[my0 + j] = run; run += c;
  }
  tsum[tid] = run; __syncthreads();
  #pragma unroll
  for (int off = 1; off < 256; off <<= 1){
    int a = (tid >= off) ? tsum[tid-off] : 0; __syncthreads();
    tsum[tid] += a; __syncthreads();
  }
  int bt = tsum[tid] - run;
  for (int j = 0; j < Tc; j++) h[my0 + j] += bt;
  __syncthreads();
  if (row0 + tid < n) rowptr[row0 + tid] = s + h[my0];
  __syncthreads();

  i = s + tid;
  for (; i + 256*7 < e; i += 256*8){
    int2 E[8];
    #pragma unroll
    for (int k = 0; k < 8; k++) E[k] = ebuf[i + 256*k];
    #pragma unroll
    for (int k = 0; k < 8; k++){
      int x = E[k].x;
      int col = x & 0xFFFFF;
      int key = ((x >> 20) & 255) * Tc + (col >> TCSH);
      int p = atomicAdd(&h[key], 1);
      ep[s + p] = make_int2(col << 7, E[k].y);   // byte offset
    }
  }
  for (; i < e; i += 256){
    int2 E = ebuf[i];
    int x = E.x;
    int col = x & 0xFFFFF;
    int key = ((x >> 20) & 255) * Tc + (col >> TCSH);
    int p = atomicAdd(&h[key], 1);
    ep[s + p] = make_int2(col << 7, E.y);
  }
}

// Row-length counting sort -> rowperm (descending length). Purpose: waves of
// one spmm block get near-equal-length rows, so block lifetime ~= mean row
// time instead of max-of-4 (the 75%-occupancy retirement tail).
__global__ __launch_bounds__(256) void lhist_kernel(const int* __restrict__ rowptr, int* __restrict__ lcnt, int n){
  __shared__ int h[256];
  h[threadIdx.x] = 0;
  __syncthreads();
  int stride = gridDim.x * 256;
  for (int r = blockIdx.x*256 + threadIdx.x; r < n; r += stride){
    int len = rowptr[r+1] - rowptr[r];
    int b = 255 - min(len, 255);        // bucket 0 = longest
    atomicAdd(&h[b], 1);
  }
  __syncthreads();
  int c = h[threadIdx.x];
  if (c) atomicAdd(&lcnt[threadIdx.x], c);
}

__global__ __launch_bounds__(256) void lscan_kernel(const int* __restrict__ lcnt, int* __restrict__ lcur){
  __shared__ int tmp[256];
  int t = threadIdx.x;
  int v = lcnt[t];
  tmp[t] = v; __syncthreads();
  #pragma unroll
  for (int off = 1; off < 256; off <<= 1){
    int a = (t >= off) ? tmp[t-off] : 0; __syncthreads();
    tmp[t] += a; __syncthreads();
  }
  lcur[t] = tmp[t] - v;   // exclusive
}

__global__ __launch_bounds__(256) void lscatter_kernel(const int* __restrict__ rowptr, int* __restrict__ lcur,
                                                       int* __restrict__ rowperm, int n){
  int stride = gridDim.x * 256;
  for (int r = blockIdx.x*256 + threadIdx.x; r < n; r += stride){
    int len = rowptr[r+1] - rowptr[r];
    int b = 255 - min(len, 255);
    int p = atomicAdd(&lcur[b], 1);
    rowperm[p] = r;
  }
}

// Shared per-row SpMM body: side[row] = bf16( sum_e val_e * ego_fp8[off_e] ).
// One wave per row. Lane i reads 8 B of row E[i>>4] at byte (i&15)*8 -> 64
// lanes span 4 random 128-B rows per VMEM instr. Steady state: 32-edge
// iterations (8 gathers in flight, no clamp/select chain); remainder uses
// the clamped 16-edge path. FMAs packed (v_pk_fma_f32); gather offset is
// E.x | (seg*8) (ep.x = col<<7, low 7 bits free).
__device__ __forceinline__ void spmm_row_body(int row, int lane,
                                              const int* __restrict__ rowptr, const int2* __restrict__ ep,
                                              const unsigned char* __restrict__ egof8,
                                              unsigned int* __restrict__ sideb){
  int s = rowptr[row], e = rowptr[row+1];
  int sub  = lane >> 4;     // which edge of the quad
  int half = lane & 15;     // which 8-byte segment of the 128-B row
  int half8 = half << 3;

  f32x2 acc2[4];
  #pragma unroll
  for (int j = 0; j < 4; j++) acc2[j] = (f32x2){0.f, 0.f};

  int base = s;
  for (; base + 32 <= e; base += 32){
    int2 E[8]; uint2 X[8];
    #pragma unroll
    for (int k = 0; k < 8; k++) E[k] = ep[base + 4*k + sub];
    #pragma unroll
    for (int k = 0; k < 8; k++)
      X[k] = *(const uint2*)(egof8 + (size_t)(unsigned)(E[k].x | half8));
    #pragma unroll
    for (int k = 0; k < 8; k++){
      float v = __int_as_float(E[k].y);
      f32x2 vv = (f32x2){v, v};
      acc2[0] = pk_fma(vv, __builtin_amdgcn_cvt_pk_f32_fp8((int)X[k].x, false), acc2[0]);
      acc2[1] = pk_fma(vv, __builtin_amdgcn_cvt_pk_f32_fp8((int)X[k].x, true ), acc2[1]);
      acc2[2] = pk_fma(vv, __builtin_amdgcn_cvt_pk_f32_fp8((int)X[k].y, false), acc2[2]);
      acc2[3] = pk_fma(vv, __builtin_amdgcn_cvt_pk_f32_fp8((int)X[k].y, true ), acc2[3]);
    }
  }
  for (; base < e; base += 16){
    int2 E[4]; uint2 X[4];
    #pragma unroll
    for (int k = 0; k < 4; k++){
      int idx = base + 4*k + sub;
      idx = idx < e ? idx : e - 1;
      E[k] = ep[idx];
    }
    #pragma unroll
    for (int k = 0; k < 4; k++)
      X[k] = *(const uint2*)(egof8 + (size_t)(unsigned)(E[k].x | half8));
    #pragma unroll
    for (int k = 0; k < 4; k++){
      float v = (base + 4*k + sub < e) ? __int_as_float(E[k].y) : 0.f;
      f32x2 vv = (f32x2){v, v};
      acc2[0] = pk_fma(vv, __builtin_amdgcn_cvt_pk_f32_fp8((int)X[k].x, false), acc2[0]);
      acc2[1] = pk_fma(vv, __builtin_amdgcn_cvt_pk_f32_fp8((int)X[k].x, true ), acc2[1]);
      acc2[2] = pk_fma(vv, __builtin_amdgcn_cvt_pk_f32_fp8((int)X[k].y, false), acc2[2]);
      acc2[3] = pk_fma(vv, __builtin_amdgcn_cvt_pk_f32_fp8((int)X[k].y, true ), acc2[3]);
    }
  }
  #pragma unroll
  for (int j = 0; j < 4; j++){
    acc2[j][0] += __shfl_xor(acc2[j][0], 16, 64);
    acc2[j][1] += __shfl_xor(acc2[j][1], 16, 64);
    acc2[j][0] += __shfl_xor(acc2[j][0], 32, 64);
    acc2[j][1] += __shfl_xor(acc2[j][1], 32, 64);
  }
  if (lane < 16){
    unsigned int o0 = pk_bf16(acc2[0][0], acc2[0][1]);
    unsigned int o1 = pk_bf16(acc2[1][0], acc2[1][1]);
    unsigned int o2 = pk_bf16(acc2[2][0], acc2[2][1]);
    unsigned int o3 = pk_bf16(acc2[3][0], acc2[3][1]);
    *(uint4*)(sideb + (size_t)row*64 + half*4) = make_uint4(o0, o1, o2, o3);
  }
}

// Full-graph SpMM: wave w -> row rowperm[w] (length-sorted, descending).
__global__ __launch_bounds__(256) void spmm_kernel(const int* __restrict__ rowptr, const int2* __restrict__ ep,
                                                   const unsigned char* __restrict__ egof8,
                                                   unsigned int* __restrict__ sideb,
                                                   const int* __restrict__ rowperm, int n){
  int w = (blockIdx.x*256 + threadIdx.x) >> 6;
  int lane = threadIdx.x & 63;
  if (w >= n) return;
  spmm_row_body(rowperm[w], lane, rowptr, ep, egof8, sideb);
}

// sample slot -> graph row (user | U+pos | U+neg)
__device__ __forceinline__ int samp_row(int slot, const int* __restrict__ user, const int* __restrict__ pos,
                                        const int* __restrict__ neg, int B, int U){
  if (slot < B)   return user[slot];
  if (slot < 2*B) return U + pos[slot - B];
  return U + neg[slot - 2*B];
}

// Last-layer SpMM restricted to sample rows. Duplicate slots compute the
// identical row -> byte-identical concurrent writes (benign).
__global__ __launch_bounds__(256) void spmm_samp_kernel(const int* __restrict__ rowptr, const int2* __restrict__ ep,
                                                        const unsigned char* __restrict__ egof8,
                                                        unsigned int* __restrict__ sideb,
                                                        const int* __restrict__ user, const int* __restrict__ pos,
                                                        const int* __restrict__ neg, int B, int U){
  int w = (blockIdx.x*256 + threadIdx.x) >> 6;
  int lane = threadIdx.x & 63;
  if (w >= 3*B) return;
  int row = samp_row(w, user, pos, neg, B, U);
  spmm_row_body(row, lane, rowptr, ep, egof8, sideb);
}

// MFMA transform: egob[r] = bf16(leaky( [side | ego.*side] @ Wc + b ));
// also writes the fp8 shadow for the next layer's spmm gather.
__global__ __launch_bounds__(256, 4) void transform_kernel(const unsigned int* __restrict__ sideb,
                                                           unsigned int* __restrict__ egob,
                                                           unsigned char* __restrict__ egof8,
                                                           const unsigned short* __restrict__ Wf,
                                                           const float* __restrict__ b1, const float* __restrict__ b2,
                                                           int n){
  __shared__ __align__(16) unsigned short X[64 * XPAD];   // 33 KB
  int row0 = blockIdx.x * 64;
  int tid = threadIdx.x;
  for (int idx = tid; idx < 64*64; idx += 256){
    int r = idx >> 6, cp = idx & 63;
    int row = row0 + r;
    unsigned int sv = 0, pv = 0;
    if (row < n){
      unsigned int s2 = sideb[(size_t)row*64 + cp];
      unsigned int eb = egob[(size_t)row*64 + cp];
      sv = s2;
      pv = (unsigned int)f2bf(bf_lo(s2) * bf_lo(eb)) | ((unsigned int)f2bf(bf_hi(s2) * bf_hi(eb)) << 16);
    }
    *(unsigned int*)&X[r*XPAD + 2*cp]       = sv;
    *(unsigned int*)&X[r*XPAD + 128 + 2*cp] = pv;
  }
  __syncthreads();

  int wave = tid >> 6, lane = tid & 63;
  int wr0 = wave * 16;
  int m = lane & 15, quad = lane >> 4;

  f32x4 acc[8];
  #pragma unroll
  for (int t = 0; t < 8; t++) acc[t] = (f32x4){0.f, 0.f, 0.f, 0.f};

  const unsigned short* arow = &X[(wr0 + m)*XPAD + quad*8];
  #pragma unroll
  for (int ks = 0; ks < 8; ks++){
    bf16x8 a = *(const bf16x8*)(arow + ks*32);
    #pragma unroll
    for (int t = 0; t < 8; t++){
      bf16x8 b = *(const bf16x8*)&Wf[((ks*8 + t)*64 + lane)*8];
      acc[t] = __builtin_amdgcn_mfma_f32_16x16x32_bf16(a, b, acc[t], 0, 0, 0);
    }
  }

  unsigned short* ego16 = (unsigned short*)egob;
  #pragma unroll
  for (int t = 0; t < 8; t++){
    int col = t*16 + m;
    float bb = b1[col] + b2[col];
    #pragma unroll
    for (int r = 0; r < 4; r++){
      int row = row0 + wr0 + quad*4 + r;
      if (row < n){
        float v = acc[t][r] + bb;
        v = v > 0.f ? v : NEG_SLOPE*v;
        ego16[(size_t)row*D + col] = f2bf(v);
        egof8[(size_t)row*D + col] =
            (unsigned char)(__builtin_amdgcn_cvt_pk_fp8_f32(v, v, 0, false) & 0xff);
      }
    }
  }
}

// Last-layer transform restricted to sample rows (no fp8 shadow: nothing
// reads it after the final layer). Duplicate rows -> identical writes.
__global__ __launch_bounds__(256, 4) void transform_samp_kernel(const unsigned int* __restrict__ sideb,
                                                                unsigned int* __restrict__ egob,
                                                                const unsigned short* __restrict__ Wf,
                                                                const float* __restrict__ b1, const float* __restrict__ b2,
                                                                const int* __restrict__ user, const int* __restrict__ pos,
                                                                const int* __restrict__ neg, int B, int U){
  __shared__ __align__(16) unsigned short X[64 * XPAD];   // 33 KB
  __shared__ int rows_l[64];
  int slot0 = blockIdx.x * 64;
  int tid = threadIdx.x;
  int total = 3*B;
  if (tid < 64){
    int slot = slot0 + tid;
    rows_l[tid] = (slot < total) ? samp_row(slot, user, pos, neg, B, U) : -1;
  }
  __syncthreads();
  for (int idx = tid; idx < 64*64; idx += 256){
    int r = idx >> 6, cp = idx & 63;
    int row = rows_l[r];
    unsigned int sv = 0, pv = 0;
    if (row >= 0){
      unsigned int s2 = sideb[(size_t)row*64 + cp];
      unsigned int eb = egob[(size_t)row*64 + cp];
      sv = s2;
      pv = (unsigned int)f2bf(bf_lo(s2) * bf_lo(eb)) | ((unsigned int)f2bf(bf_hi(s2) * bf_hi(eb)) << 16);
    }
    *(unsigned int*)&X[r*XPAD + 2*cp]       = sv;
    *(unsigned int*)&X[r*XPAD + 128 + 2*cp] = pv;
  }
  __syncthreads();

  int wave = tid >> 6, lane = tid & 63;
  int wr0 = wave * 16;
  int m = lane & 15, quad = lane >> 4;

  f32x4 acc[8];
  #pragma unroll
  for (int t = 0; t < 8; t++) acc[t] = (f32x4){0.f, 0.f, 0.f, 0.f};

  const unsigned short* arow = &X[(wr0 + m)*XPAD + quad*8];
  #pragma unroll
  for (int ks = 0; ks < 8; ks++){
    bf16x8 a = *(const bf16x8*)(arow + ks*32);
    #pragma unroll
    for (int t = 0; t < 8; t++){
      bf16x8 b = *(const bf16x8*)&Wf[((ks*8 + t)*64 + lane)*8];
      acc[t] = __builtin_amdgcn_mfma_f32_16x16x32_bf16(a, b, acc[t], 0, 0, 0);
    }
  }

  unsigned short* ego16 = (unsigned short*)egob;
  #pragma unroll
  for (int t = 0; t < 8; t++){
    int col = t*16 + m;
    float bb = b1[col] + b2[col];
    #pragma unroll
    for (int r = 0; r < 4; r++){
      int row = rows_l[wr0 + quad*4 + r];
      if (row >= 0){
        float v = acc[t][r] + bb;
        v = v > 0.f ? v : NEG_SLOPE*v;
        ego16[(size_t)row*D + col] = f2bf(v);
      }
    }
  }
}

// Per-sample dot contributions of the current block (bf16 base).
__global__ __launch_bounds__(256) void score_kernel(const unsigned int* __restrict__ egob, const int* __restrict__ user,
                                                    const int* __restrict__ pos, const int* __restrict__ neg,
                                                    float* __restrict__ pacc, float* __restrict__ nacc,
                                                    int B, int U, int normalize){
  int w = (blockIdx.x*256 + threadIdx.x) >> 6;
  int lane = threadIdx.x & 63;
  if (w >= B) return;
  size_t ur = (size_t)user[w] * 64;
  size_t pr = ((size_t)U + pos[w]) * 64;
  size_t nr = ((size_t)U + neg[w]) * 64;
  unsigned int ub = egob[ur + lane], pb = egob[pr + lane], nb = egob[nr + lane];
  float ux = bf_lo(ub), uy = bf_hi(ub);
  float px = bf_lo(pb), py = bf_hi(pb);
  float nx = bf_lo(nb), ny = bf_hi(nb);
  float dup = ux*px + uy*py;
  float dun = ux*nx + uy*ny;
  float nu  = ux*ux + uy*uy;
  float np  = px*px + py*py;
  float nn  = nx*nx + ny*ny;
  dup = wave_red(dup); dun = wave_red(dun);
  nu = wave_red(nu); np = wave_red(np); nn = wave_red(nn);
  if (lane == 0){
    if (normalize){
      float inu = 1.f / fmaxf(sqrtf(nu), NORM_EPS);
      float inp = 1.f / fmaxf(sqrtf(np), NORM_EPS);
      float inn = 1.f / fmaxf(sqrtf(nn), NORM_EPS);
      pacc[w] += dup * inu * inp;
      nacc[w] += dun * inu * inn;
    } else {
      pacc[w] += dup;
      nacc[w] += dun;
    }
  }
}

__global__ __launch_bounds__(256) void reg_kernel(const float* __restrict__ item, const int* __restrict__ pos,
                                                  const int* __restrict__ neg, float* __restrict__ reg_out, int B){
  int w = (blockIdx.x*256 + threadIdx.x) >> 6;
  int lane = threadIdx.x & 63;
  if (w >= B) return;
  const float2* it = (const float2*)item;
  float2 pv = it[(size_t)pos[w]*64 + lane];
  float2 nv = it[(size_t)neg[w]*64 + lane];
  float v = pv.x*pv.x + pv.y*pv.y + nv.x*nv.x + nv.y*nv.y;
  v = wave_red(v);
  if (lane == 0) atomicAdd(reg_out, v);
}

__global__ __launch_bounds__(256) void final_kernel(const float* __restrict__ pacc, const float* __restrict__ nacc,
                                                    const float* __restrict__ reg_sum, float* __restrict__ out, int B){
  __shared__ float red[256];
  float s = 0.f;
  for (int i = threadIdx.x; i < B; i += 256){
    float x = nacc[i] - pacc[i];
    s += (x > 0.f) ? x + log1pf(expf(-x)) : log1pf(expf(x));   // softplus, stable
  }
  red[threadIdx.x] = s; __syncthreads();
  for (int o = 128; o > 0; o >>= 1){
    if (threadIdx.x < o) red[threadIdx.x] += red[threadIdx.x + o];
    __syncthreads();
  }
  if (threadIdx.x == 0){
    out[0] = red[0] / (float)B;
    out[1] = REG_LAMBDA * 0.5f * reg_sum[0] / (float)B;
  }
}

extern "C" void kernel_launch(void* const* d_in, const int* in_sizes, int n_in,
                              void* d_out, int out_size, void* d_ws, size_t ws_size,
                              hipStream_t stream) {
  const int*   user = (const int*)d_in[0];
  const int*   pos  = (const int*)d_in[1];
  const int*   neg  = (const int*)d_in[2];
  const int*   erow = (const int*)d_in[3];
  const int*   ecol = (const int*)d_in[4];
  const float* eval = (const float*)d_in[5];
  const float* uemb = (const float*)d_in[6];
  const float* iemb = (const float*)d_in[7];
  const float* Wg   = (const float*)d_in[8];
  const float* bg   = (const float*)d_in[9];
  const float* Wb   = (const float*)d_in[10];
  const float* bb   = (const float*)d_in[11];

  int B   = in_sizes[0];
  int NNZ = in_sizes[3];
  int U   = in_sizes[6] / D;
  int I   = in_sizes[7] / D;
  int N   = U + I;
  int L   = in_sizes[9] / D;
  int nbk = (N + RPB - 1) >> RPB_SHIFT;
  int Tc  = (N + (1 << TCSH) - 1) >> TCSH;

  char* wsp = (char*)d_ws;
  auto alloc = [&](size_t bytes) -> char* {
    char* p = wsp; wsp += (bytes + 255) & ~(size_t)255; return p;
  };
  size_t side_bytes = (size_t)N * D * 2;
  size_t ebuf_bytes = (size_t)NNZ * 8;
  unsigned int*  sideb  = (unsigned int*)alloc(side_bytes > ebuf_bytes ? side_bytes : ebuf_bytes);
  unsigned int*  egob   = (unsigned int*)alloc((size_t)N * D * 2);     // bf16 ego, pair-packed
  unsigned short* egof8 = (unsigned short*)alloc((size_t)N * D);       // fp8-e4m3 ego, pair-packed
  int2*          ep     = (int2*) alloc((size_t)NNZ * 8);              // CSR edges (byte-off, val)
  unsigned short* Wf    = (unsigned short*)alloc((size_t)L * 256 * D * 2);
  int*           rowptr = (int*)  alloc((size_t)(N + 1) * 4);
  int*           bcnt   = (int*)  alloc((size_t)MAXB * 4);
  int*           bbase  = (int*)  alloc((size_t)(MAXB + 1) * 4);
  int*           bcur   = (int*)  alloc((size_t)MAXB * 4);
  int*           lcnt   = (int*)  alloc(256 * 4);
  int*           lcur   = (int*)  alloc(256 * 4);
  int*           rowperm= (int*)  alloc((size_t)N * 4);
  float*         pacc   = (float*)alloc((size_t)B * 4);
  float*         nacc   = (float*)alloc((size_t)B * 4);
  float*         regs   = (float*)alloc(256);
  int2*          ebuf   = (int2*)sideb;   // staging alias (build phase only)

  hipMemsetAsync(bcnt, 0, (size_t)nbk * 4, stream);
  hipMemsetAsync(lcnt, 0, 256 * 4, stream);
  hipMemsetAsync(pacc, 0, (size_t)B * 4, stream);
  hipMemsetAsync(nacc, 0, (size_t)B * 4, stream);
  hipMemsetAsync(regs, 0, 4, stream);

  toq_kernel<<<(U*64 + 255) / 256, 256, 0, stream>>>(uemb, egob, egof8, U*64);
  toq_kernel<<<(I*64 + 255) / 256, 256, 0, stream>>>(iemb, egob + (size_t)U*64, egof8 + (size_t)U*64, I*64);
  wconv_kernel<<<(L*256*D + 255) / 256, 256, 0, stream>>>(Wg, Wb, Wf, L);

  // Bucketed CSR build (edges within a row ordered by col-tile)
  bhist_kernel<<<2048, 256, 0, stream>>>(erow, bcnt, NNZ, nbk);
  bscan_kernel<<<1, 1024, 0, stream>>>(bcnt, bbase, bcur, rowptr, nbk, NNZ, N);
  bscatter_kernel<<<(NNZ + CHUNK - 1) / CHUNK, 256, 0, stream>>>(erow, ecol, eval, bcur, ebuf, NNZ, nbk);
  fscatter_kernel<<<nbk, 256, 0, stream>>>(ebuf, bbase, ep, rowptr, Tc, N);

  // Row permutation: descending length (spmm block-retirement balance)
  lhist_kernel<<<1024, 256, 0, stream>>>(rowptr, lcnt, N);
  lscan_kernel<<<1, 256, 0, stream>>>(lcnt, lcur);
  lscatter_kernel<<<1024, 256, 0, stream>>>(rowptr, lcur, rowperm, N);

  // Block 0 (raw embeddings, un-normalized)
  score_kernel<<<(B + 3) / 4, 256, 0, stream>>>(egob, user, pos, neg, pacc, nacc, B, U, 0);

  int sampledN = 3 * B;
  bool use_samp = (sampledN < N);

  for (int l = 0; l < L; l++){
    if (use_samp && l == L - 1){
      // Final layer: only rows read by the loss (user | U+pos | U+neg).
      spmm_samp_kernel<<<(sampledN + 3) / 4, 256, 0, stream>>>(
          rowptr, ep, (const unsigned char*)egof8, sideb, user, pos, neg, B, U);
      transform_samp_kernel<<<(sampledN + 63) / 64, 256, 0, stream>>>(
          sideb, egob, Wf + (size_t)l * 256 * D,
          bg + (size_t)l * D, bb + (size_t)l * D, user, pos, neg, B, U);
    } else {
      spmm_kernel<<<(N + 3) / 4, 256, 0, stream>>>(rowptr, ep, (const unsigned char*)egof8, sideb, rowperm, N);
      transform_kernel<<<(N + 63) / 64, 256, 0, stream>>>(
          sideb, egob, (unsigned char*)egof8, Wf + (size_t)l * 256 * D,
          bg + (size_t)l * D, bb + (size_t)l * D, N);
    }
    score_kernel<<<(B + 3) / 4, 256, 0, stream>>>(egob, user, pos, neg, pacc, nacc, B, U, 1);
  }

  reg_kernel<<<(B + 3) / 4, 256, 0, stream>>>(iemb, pos, neg, regs, B);
  final_kernel<<<1, 256, 0, stream>>>(pacc, nacc, regs, (float*)d_out, B);
}

// Round 9
// 782.717 us; speedup vs baseline: 1.3392x; 1.3392x over previous
//
#include <hip/hip_runtime.h>
#include <math.h>

#define D 128
#define NEG_SLOPE 0.2f
#define REG_LAMBDA 1e-4f
#define NORM_EPS 1e-12f

#define RPB 256          // rows per coarse bucket
#define RPB_SHIFT 8
#define MAXB 1024        // max coarse buckets (N <= 262144)
#define CHUNK 2048       // edges per bscatter block (33 KB LDS -> 4 blocks/CU)
#define TCSH 14          // 16384 cols per col-tile (for within-row edge ordering)
#define KEYMAX 4096      // 256 rows * Tc ; Tc<=16 -> N <= 262144

#define XPAD 264         // padded LDS row stride in bf16 elems (256 + 8)

using bf16x8 = __attribute__((ext_vector_type(8))) short;
using f32x4  = __attribute__((ext_vector_type(4))) float;
using f32x2  = __attribute__((ext_vector_type(2))) float;

__device__ __forceinline__ float wave_red(float v){
  #pragma unroll
  for (int o = 32; o > 0; o >>= 1) v += __shfl_xor(v, o, 64);
  return v;
}

__device__ __forceinline__ unsigned short f2bf(float f){
  unsigned int u = __float_as_uint(f);
  unsigned int r = (u + 0x7fffu + ((u >> 16) & 1u)) >> 16;  // RNE
  return (unsigned short)r;
}
__device__ __forceinline__ float bf_lo(unsigned int x){ return __uint_as_float(x << 16); }
__device__ __forceinline__ float bf_hi(unsigned int x){ return __uint_as_float(x & 0xffff0000u); }

// packed 2xf32 FMA (VOP3P): d = a*b + c on both halves
__device__ __forceinline__ f32x2 pk_fma(f32x2 a, f32x2 b, f32x2 c){
  f32x2 d;
  asm("v_pk_fma_f32 %0, %1, %2, %3" : "=v"(d) : "v"(a), "v"(b), "v"(c));
  return d;
}
// hardware 2xf32 -> packed bf16 (RNE)
__device__ __forceinline__ unsigned int pk_bf16(float lo, float hi){
  unsigned int d;
  asm("v_cvt_pk_bf16_f32 %0, %1, %2" : "=v"(d) : "v"(lo), "v"(hi));
  return d;
}

// fp32 pair -> (bf16 pair packed in uint, fp8-e4m3 pair packed in ushort)
__global__ __launch_bounds__(256) void toq_kernel(const float* __restrict__ src, unsigned int* __restrict__ dstb,
                                                  unsigned short* __restrict__ dst8, int npairs){
  int i = blockIdx.x*256 + threadIdx.x;
  if (i >= npairs) return;
  float2 v = ((const float2*)src)[i];
  dstb[i] = (unsigned int)f2bf(v.x) | ((unsigned int)f2bf(v.y) << 16);
  int p = __builtin_amdgcn_cvt_pk_fp8_f32(v.x, v.y, 0, false);
  dst8[i] = (unsigned short)(p & 0xffff);
}

// W_gcn/W_bi (fp32 row-major) -> per-layer MFMA B-fragment order bf16.
__global__ __launch_bounds__(256) void wconv_kernel(const float* __restrict__ Wg, const float* __restrict__ Wb,
                                                    unsigned short* __restrict__ Wf, int L){
  int idx = blockIdx.x*256 + threadIdx.x;
  int total = L * 256 * D;
  if (idx >= total) return;
  int l = idx >> 15;
  int rem = idx & 32767;
  int k = rem >> 7;
  int n = rem & 127;
  float v = (k < 128) ? Wg[((size_t)l*128 + k)*D + n] : Wb[((size_t)l*128 + (k-128))*D + n];
  int ks = k >> 5, quad = (k >> 3) & 3, j = k & 7;
  int t = n >> 4, ln = (quad << 4) | (n & 15);
  Wf[(size_t)l*32768 + (((ks*8 + t)*64 + ln)*8 + j)] = f2bf(v);
}

// K1: coarse bucket histogram, LDS-aggregated, loads batched 4-wide
__global__ __launch_bounds__(256) void bhist_kernel(const int* __restrict__ erow, int* __restrict__ bcnt, int nnz, int nbk){
  __shared__ int h[MAXB];
  for (int i = threadIdx.x; i < nbk; i += 256) h[i] = 0;
  __syncthreads();
  int stride = gridDim.x * 256;
  int e = blockIdx.x*256 + threadIdx.x;
  for (; e + 3*stride < nnz; e += 4*stride){
    int r0 = erow[e], r1 = erow[e+stride], r2 = erow[e+2*stride], r3 = erow[e+3*stride];
    atomicAdd(&h[r0 >> RPB_SHIFT], 1);
    atomicAdd(&h[r1 >> RPB_SHIFT], 1);
    atomicAdd(&h[r2 >> RPB_SHIFT], 1);
    atomicAdd(&h[r3 >> RPB_SHIFT], 1);
  }
  for (; e < nnz; e += stride)
    atomicAdd(&h[erow[e] >> RPB_SHIFT], 1);
  __syncthreads();
  for (int i = threadIdx.x; i < nbk; i += 256){
    int c = h[i];
    if (c) atomicAdd(&bcnt[i], c);
  }
}

// K2: exclusive scan of bucket counts (single block)
__global__ __launch_bounds__(1024) void bscan_kernel(const int* __restrict__ bcnt, int* __restrict__ bbase,
                                                     int* __restrict__ bcur, int* __restrict__ rowptr,
                                                     int nbk, int nnz, int n){
  __shared__ int tmp[1024];
  int t = threadIdx.x;
  int v = (t < nbk) ? bcnt[t] : 0;
  tmp[t] = v; __syncthreads();
  #pragma unroll
  for (int off = 1; off < 1024; off <<= 1){
    int a = (t >= off) ? tmp[t-off] : 0; __syncthreads();
    tmp[t] += a; __syncthreads();
  }
  if (t < nbk){ int b = tmp[t] - v; bbase[t] = b; bcur[t] = b; }
  if (t == 0){ bbase[nbk] = nnz; rowptr[n] = nnz; }
}

// K3: coarse scatter. Block sorts a CHUNK of edges by bucket in LDS, reserves
// global ranges, writes coalesced runs. ebuf.x = col | (row_low8 << 20).
__global__ __launch_bounds__(256) void bscatter_kernel(const int* __restrict__ erow, const int* __restrict__ ecol,
                                                       const float* __restrict__ eval, int* __restrict__ bcur,
                                                       int2* __restrict__ ebuf, int nnz, int nbk){
  __shared__ int2 ls[CHUNK];
  __shared__ int gdst[CHUNK];
  __shared__ int h[MAXB];
  __shared__ int hx[MAXB];
  __shared__ int tmp[256];
  int tid = threadIdx.x;
  int base = blockIdx.x * CHUNK;
  int cn = min(CHUNK, nnz - base);
  bool full = (cn == CHUNK);
  for (int i = tid; i < nbk; i += 256) h[i] = 0;
  __syncthreads();

  int r[8];
  if (full){
    #pragma unroll
    for (int k = 0; k < 8; k++) r[k] = erow[base + tid + 256*k];
    #pragma unroll
    for (int k = 0; k < 8; k++) atomicAdd(&h[r[k] >> RPB_SHIFT], 1);
  } else {
    #pragma unroll
    for (int k = 0; k < 8; k++){
      int i = tid + 256*k;
      r[k] = (i < cn) ? erow[base + i] : -1;
    }
    #pragma unroll
    for (int k = 0; k < 8; k++)
      if (r[k] >= 0) atomicAdd(&h[r[k] >> RPB_SHIFT], 1);
  }
  __syncthreads();

  int b0 = tid*4;
  int c0=0,c1=0,c2=0,c3=0;
  if (b0 < nbk){
    c0 = h[b0];
    if (b0+1 < nbk) c1 = h[b0+1];
    if (b0+2 < nbk) c2 = h[b0+2];
    if (b0+3 < nbk) c3 = h[b0+3];
  }
  int tsum = c0+c1+c2+c3;
  tmp[tid] = tsum; __syncthreads();
  #pragma unroll
  for (int off = 1; off < 256; off <<= 1){
    int a = (tid >= off) ? tmp[tid-off] : 0; __syncthreads();
    tmp[tid] += a; __syncthreads();
  }
  int tbase = tmp[tid] - tsum;
  if (b0 < nbk){
    hx[b0] = tbase;
    if (b0+1 < nbk) hx[b0+1] = tbase + c0;
    if (b0+2 < nbk) hx[b0+2] = tbase + c0 + c1;
    if (b0+3 < nbk) hx[b0+3] = tbase + c0 + c1 + c2;
  }
  __syncthreads();
  for (int i = tid; i < nbk; i += 256){
    int c = h[i];
    if (c > 0){
      int gb = atomicAdd(&bcur[i], c);
      h[i] = gb - hx[i];
    }
  }
  __syncthreads();

  if (full){
    int c[8]; float v[8];
    #pragma unroll
    for (int k = 0; k < 8; k++) c[k] = ecol[base + tid + 256*k];
    #pragma unroll
    for (int k = 0; k < 8; k++) v[k] = eval[base + tid + 256*k];
    #pragma unroll
    for (int k = 0; k < 8; k++){
      int rr = r[k];
      int b = rr >> RPB_SHIFT;
      int x = c[k] | ((rr & (RPB-1)) << 20);
      int lpos = atomicAdd(&hx[b], 1);
      ls[lpos] = make_int2(x, __float_as_int(v[k]));
      gdst[lpos] = h[b] + lpos;
    }
  } else {
    for (int i = tid; i < cn; i += 256){
      int rr = erow[base+i];
      int b = rr >> RPB_SHIFT;
      int x = ecol[base+i] | ((rr & (RPB-1)) << 20);
      int lpos = atomicAdd(&hx[b], 1);
      ls[lpos] = make_int2(x, __float_as_int(eval[base+i]));
      gdst[lpos] = h[b] + lpos;
    }
  }
  __syncthreads();
  if (full){
    #pragma unroll
    for (int k = 0; k < 8; k++){
      int i = tid + 256*k;
      ebuf[gdst[i]] = ls[i];
    }
  } else {
    for (int i = tid; i < cn; i += 256)
      ebuf[gdst[i]] = ls[i];
  }
}

// K4: one block per coarse bucket. Counting sort by key = (row_low8, col-tile)
// -> rowptr + final CSR (edges within a row ordered by col-tile).
// ep.x = byte offset into fp8 table (col * 128). Both passes batched 8-wide.
__global__ __launch_bounds__(256) void fscatter_kernel(const int2* __restrict__ ebuf, const int* __restrict__ bbase,
                                                       int2* __restrict__ ep, int* __restrict__ rowptr,
                                                       int Tc, int n){
  __shared__ int h[KEYMAX];
  __shared__ int tsum[256];
  int b = blockIdx.x;
  int tid = threadIdx.x;
  int s = bbase[b], e = bbase[b+1];
  int row0 = b << RPB_SHIFT;
  int nk = 256 * Tc;
  for (int i = tid; i < nk; i += 256) h[i] = 0;
  __syncthreads();

  int i = s + tid;
  for (; i + 256*7 < e; i += 256*8){
    int x[8];
    #pragma unroll
    for (int k = 0; k < 8; k++) x[k] = ebuf[i + 256*k].x;
    #pragma unroll
    for (int k = 0; k < 8; k++){
      int key = ((x[k] >> 20) & 255) * Tc + ((x[k] & 0xFFFFF) >> TCSH);
      atomicAdd(&h[key], 1);
    }
  }
  for (; i < e; i += 256){
    int x = ebuf[i].x;
    int key = ((x >> 20) & 255) * Tc + ((x & 0xFFFFF) >> TCSH);
    atomicAdd(&h[key], 1);
  }
  __syncthreads();
  // exclusive scan: thread tid owns keys of row tid (segment of Tc)
  int my0 = tid * Tc;
  int run = 0;
  for (int j = 0; j < Tc; j++){
    int c = h[my0 + j]; h[my0 + j] = run; run += c;
  }
  tsum[tid] = run; __syncthreads();
  #pragma unroll
  for (int off = 1; off < 256; off <<= 1){
    int a = (tid >= off) ? tsum[tid-off] : 0; __syncthreads();
    tsum[tid] += a; __syncthreads();
  }
  int bt = tsum[tid] - run;
  for (int j = 0; j < Tc; j++) h[my0 + j] += bt;
  __syncthreads();
  if (row0 + tid < n) rowptr[row0 + tid] = s + h[my0];
  __syncthreads();

  i = s + tid;
  for (; i + 256*7 < e; i += 256*8){
    int2 E[8];
    #pragma unroll
    for (int k = 0; k < 8; k++) E[k] = ebuf[i + 256*k];
    #pragma unroll
    for (int k = 0; k < 8; k++){
      int x = E[k].x;
      int col = x & 0xFFFFF;
      int key = ((x >> 20) & 255) * Tc + (col >> TCSH);
      int p = atomicAdd(&h[key], 1);
      ep[s + p] = make_int2(col << 7, E[k].y);   // byte offset
    }
  }
  for (; i < e; i += 256){
    int2 E = ebuf[i];
    int x = E.x;
    int col = x & 0xFFFFF;
    int key = ((x >> 20) & 255) * Tc + (col >> TCSH);
    int p = atomicAdd(&h[key], 1);
    ep[s + p] = make_int2(col << 7, E.y);
  }
}

// Row-length counting sort -> rowperm (descending length). Purpose: waves of
// one spmm block get near-equal-length rows, so block lifetime ~= mean row
// time instead of max-of-4 (the 75%-occupancy retirement tail).
__global__ __launch_bounds__(256) void lhist_kernel(const int* __restrict__ rowptr, int* __restrict__ lcnt, int n){
  __shared__ int h[256];
  h[threadIdx.x] = 0;
  __syncthreads();
  int stride = gridDim.x * 256;
  for (int r = blockIdx.x*256 + threadIdx.x; r < n; r += stride){
    int len = rowptr[r+1] - rowptr[r];
    int b = 255 - min(len, 255);        // bucket 0 = longest
    atomicAdd(&h[b], 1);
  }
  __syncthreads();
  int c = h[threadIdx.x];
  if (c) atomicAdd(&lcnt[threadIdx.x], c);
}

__global__ __launch_bounds__(256) void lscan_kernel(const int* __restrict__ lcnt, int* __restrict__ lcur){
  __shared__ int tmp[256];
  int t = threadIdx.x;
  int v = lcnt[t];
  tmp[t] = v; __syncthreads();
  #pragma unroll
  for (int off = 1; off < 256; off <<= 1){
    int a = (t >= off) ? tmp[t-off] : 0; __syncthreads();
    tmp[t] += a; __syncthreads();
  }
  lcur[t] = tmp[t] - v;   // exclusive
}

// R9 fix (was 270 us from 150K global atomics-with-return on ~30 hot
// addresses, ~50ns serialized each — Guideline 12): block-local ranking.
// Each block owns a contiguous row chunk; LDS histogram -> ONE global
// atomicAdd per non-empty bucket per block reserves a range -> LDS atomics
// hand out slots. Global same-address atomics drop 150K -> ~8K.
__global__ __launch_bounds__(256) void lscatter_kernel(const int* __restrict__ rowptr, int* __restrict__ lcur,
                                                       int* __restrict__ rowperm, int n){
  __shared__ int h[256];
  __shared__ int hx[256];
  int tid = threadIdx.x;
  int chunk = (n + gridDim.x - 1) / gridDim.x;
  int r0 = blockIdx.x * chunk;
  int r1 = min(r0 + chunk, n);
  if (r0 >= n) return;
  h[tid] = 0;
  __syncthreads();
  for (int r = r0 + tid; r < r1; r += 256){
    int len = rowptr[r+1] - rowptr[r];
    int b = 255 - min(len, 255);
    atomicAdd(&h[b], 1);
  }
  __syncthreads();
  int c = h[tid];
  hx[tid] = (c > 0) ? atomicAdd(&lcur[tid], c) : 0;
  __syncthreads();
  for (int r = r0 + tid; r < r1; r += 256){
    int len = rowptr[r+1] - rowptr[r];
    int b = 255 - min(len, 255);
    int p = atomicAdd(&hx[b], 1);
    rowperm[p] = r;
  }
}

// Shared per-row SpMM body: side[row] = bf16( sum_e val_e * ego_fp8[off_e] ).
// One wave per row. Lane i reads 8 B of row E[i>>4] at byte (i&15)*8 -> 64
// lanes span 4 random 128-B rows per VMEM instr. Steady state: 32-edge
// iterations (8 gathers in flight, no clamp/select chain); remainder uses
// the clamped 16-edge path. FMAs packed (v_pk_fma_f32); gather offset is
// E.x | (seg*8) (ep.x = col<<7, low 7 bits free).
__device__ __forceinline__ void spmm_row_body(int row, int lane,
                                              const int* __restrict__ rowptr, const int2* __restrict__ ep,
                                              const unsigned char* __restrict__ egof8,
                                              unsigned int* __restrict__ sideb){
  int s = rowptr[row], e = rowptr[row+1];
  int sub  = lane >> 4;     // which edge of the quad
  int half = lane & 15;     // which 8-byte segment of the 128-B row
  int half8 = half << 3;

  f32x2 acc2[4];
  #pragma unroll
  for (int j = 0; j < 4; j++) acc2[j] = (f32x2){0.f, 0.f};

  int base = s;
  for (; base + 32 <= e; base += 32){
    int2 E[8]; uint2 X[8];
    #pragma unroll
    for (int k = 0; k < 8; k++) E[k] = ep[base + 4*k + sub];
    #pragma unroll
    for (int k = 0; k < 8; k++)
      X[k] = *(const uint2*)(egof8 + (size_t)(unsigned)(E[k].x | half8));
    #pragma unroll
    for (int k = 0; k < 8; k++){
      float v = __int_as_float(E[k].y);
      f32x2 vv = (f32x2){v, v};
      acc2[0] = pk_fma(vv, __builtin_amdgcn_cvt_pk_f32_fp8((int)X[k].x, false), acc2[0]);
      acc2[1] = pk_fma(vv, __builtin_amdgcn_cvt_pk_f32_fp8((int)X[k].x, true ), acc2[1]);
      acc2[2] = pk_fma(vv, __builtin_amdgcn_cvt_pk_f32_fp8((int)X[k].y, false), acc2[2]);
      acc2[3] = pk_fma(vv, __builtin_amdgcn_cvt_pk_f32_fp8((int)X[k].y, true ), acc2[3]);
    }
  }
  for (; base < e; base += 16){
    int2 E[4]; uint2 X[4];
    #pragma unroll
    for (int k = 0; k < 4; k++){
      int idx = base + 4*k + sub;
      idx = idx < e ? idx : e - 1;
      E[k] = ep[idx];
    }
    #pragma unroll
    for (int k = 0; k < 4; k++)
      X[k] = *(const uint2*)(egof8 + (size_t)(unsigned)(E[k].x | half8));
    #pragma unroll
    for (int k = 0; k < 4; k++){
      float v = (base + 4*k + sub < e) ? __int_as_float(E[k].y) : 0.f;
      f32x2 vv = (f32x2){v, v};
      acc2[0] = pk_fma(vv, __builtin_amdgcn_cvt_pk_f32_fp8((int)X[k].x, false), acc2[0]);
      acc2[1] = pk_fma(vv, __builtin_amdgcn_cvt_pk_f32_fp8((int)X[k].x, true ), acc2[1]);
      acc2[2] = pk_fma(vv, __builtin_amdgcn_cvt_pk_f32_fp8((int)X[k].y, false), acc2[2]);
      acc2[3] = pk_fma(vv, __builtin_amdgcn_cvt_pk_f32_fp8((int)X[k].y, true ), acc2[3]);
    }
  }
  #pragma unroll
  for (int j = 0; j < 4; j++){
    acc2[j][0] += __shfl_xor(acc2[j][0], 16, 64);
    acc2[j][1] += __shfl_xor(acc2[j][1], 16, 64);
    acc2[j][0] += __shfl_xor(acc2[j][0], 32, 64);
    acc2[j][1] += __shfl_xor(acc2[j][1], 32, 64);
  }
  if (lane < 16){
    unsigned int o0 = pk_bf16(acc2[0][0], acc2[0][1]);
    unsigned int o1 = pk_bf16(acc2[1][0], acc2[1][1]);
    unsigned int o2 = pk_bf16(acc2[2][0], acc2[2][1]);
    unsigned int o3 = pk_bf16(acc2[3][0], acc2[3][1]);
    *(uint4*)(sideb + (size_t)row*64 + half*4) = make_uint4(o0, o1, o2, o3);
  }
}

// Full-graph SpMM: wave w -> row rowperm[w] (length-sorted, descending).
__global__ __launch_bounds__(256) void spmm_kernel(const int* __restrict__ rowptr, const int2* __restrict__ ep,
                                                   const unsigned char* __restrict__ egof8,
                                                   unsigned int* __restrict__ sideb,
                                                   const int* __restrict__ rowperm, int n){
  int w = (blockIdx.x*256 + threadIdx.x) >> 6;
  int lane = threadIdx.x & 63;
  if (w >= n) return;
  spmm_row_body(rowperm[w], lane, rowptr, ep, egof8, sideb);
}

// sample slot -> graph row (user | U+pos | U+neg)
__device__ __forceinline__ int samp_row(int slot, const int* __restrict__ user, const int* __restrict__ pos,
                                        const int* __restrict__ neg, int B, int U){
  if (slot < B)   return user[slot];
  if (slot < 2*B) return U + pos[slot - B];
  return U + neg[slot - 2*B];
}

// Last-layer SpMM restricted to sample rows. Duplicate slots compute the
// identical row -> byte-identical concurrent writes (benign).
__global__ __launch_bounds__(256) void spmm_samp_kernel(const int* __restrict__ rowptr, const int2* __restrict__ ep,
                                                        const unsigned char* __restrict__ egof8,
                                                        unsigned int* __restrict__ sideb,
                                                        const int* __restrict__ user, const int* __restrict__ pos,
                                                        const int* __restrict__ neg, int B, int U){
  int w = (blockIdx.x*256 + threadIdx.x) >> 6;
  int lane = threadIdx.x & 63;
  if (w >= 3*B) return;
  int row = samp_row(w, user, pos, neg, B, U);
  spmm_row_body(row, lane, rowptr, ep, egof8, sideb);
}

// MFMA transform: egob[r] = bf16(leaky( [side | ego.*side] @ Wc + b ));
// also writes the fp8 shadow for the next layer's spmm gather.
__global__ __launch_bounds__(256, 4) void transform_kernel(const unsigned int* __restrict__ sideb,
                                                           unsigned int* __restrict__ egob,
                                                           unsigned char* __restrict__ egof8,
                                                           const unsigned short* __restrict__ Wf,
                                                           const float* __restrict__ b1, const float* __restrict__ b2,
                                                           int n){
  __shared__ __align__(16) unsigned short X[64 * XPAD];   // 33 KB
  int row0 = blockIdx.x * 64;
  int tid = threadIdx.x;
  for (int idx = tid; idx < 64*64; idx += 256){
    int r = idx >> 6, cp = idx & 63;
    int row = row0 + r;
    unsigned int sv = 0, pv = 0;
    if (row < n){
      unsigned int s2 = sideb[(size_t)row*64 + cp];
      unsigned int eb = egob[(size_t)row*64 + cp];
      sv = s2;
      pv = (unsigned int)f2bf(bf_lo(s2) * bf_lo(eb)) | ((unsigned int)f2bf(bf_hi(s2) * bf_hi(eb)) << 16);
    }
    *(unsigned int*)&X[r*XPAD + 2*cp]       = sv;
    *(unsigned int*)&X[r*XPAD + 128 + 2*cp] = pv;
  }
  __syncthreads();

  int wave = tid >> 6, lane = tid & 63;
  int wr0 = wave * 16;
  int m = lane & 15, quad = lane >> 4;

  f32x4 acc[8];
  #pragma unroll
  for (int t = 0; t < 8; t++) acc[t] = (f32x4){0.f, 0.f, 0.f, 0.f};

  const unsigned short* arow = &X[(wr0 + m)*XPAD + quad*8];
  #pragma unroll
  for (int ks = 0; ks < 8; ks++){
    bf16x8 a = *(const bf16x8*)(arow + ks*32);
    #pragma unroll
    for (int t = 0; t < 8; t++){
      bf16x8 b = *(const bf16x8*)&Wf[((ks*8 + t)*64 + lane)*8];
      acc[t] = __builtin_amdgcn_mfma_f32_16x16x32_bf16(a, b, acc[t], 0, 0, 0);
    }
  }

  unsigned short* ego16 = (unsigned short*)egob;
  #pragma unroll
  for (int t = 0; t < 8; t++){
    int col = t*16 + m;
    float bb = b1[col] + b2[col];
    #pragma unroll
    for (int r = 0; r < 4; r++){
      int row = row0 + wr0 + quad*4 + r;
      if (row < n){
        float v = acc[t][r] + bb;
        v = v > 0.f ? v : NEG_SLOPE*v;
        ego16[(size_t)row*D + col] = f2bf(v);
        egof8[(size_t)row*D + col] =
            (unsigned char)(__builtin_amdgcn_cvt_pk_fp8_f32(v, v, 0, false) & 0xff);
      }
    }
  }
}

// Last-layer transform restricted to sample rows (no fp8 shadow: nothing
// reads it after the final layer). Duplicate rows -> identical writes.
__global__ __launch_bounds__(256, 4) void transform_samp_kernel(const unsigned int* __restrict__ sideb,
                                                                unsigned int* __restrict__ egob,
                                                                const unsigned short* __restrict__ Wf,
                                                                const float* __restrict__ b1, const float* __restrict__ b2,
                                                                const int* __restrict__ user, const int* __restrict__ pos,
                                                                const int* __restrict__ neg, int B, int U){
  __shared__ __align__(16) unsigned short X[64 * XPAD];   // 33 KB
  __shared__ int rows_l[64];
  int slot0 = blockIdx.x * 64;
  int tid = threadIdx.x;
  int total = 3*B;
  if (tid < 64){
    int slot = slot0 + tid;
    rows_l[tid] = (slot < total) ? samp_row(slot, user, pos, neg, B, U) : -1;
  }
  __syncthreads();
  for (int idx = tid; idx < 64*64; idx += 256){
    int r = idx >> 6, cp = idx & 63;
    int row = rows_l[r];
    unsigned int sv = 0, pv = 0;
    if (row >= 0){
      unsigned int s2 = sideb[(size_t)row*64 + cp];
      unsigned int eb = egob[(size_t)row*64 + cp];
      sv = s2;
      pv = (unsigned int)f2bf(bf_lo(s2) * bf_lo(eb)) | ((unsigned int)f2bf(bf_hi(s2) * bf_hi(eb)) << 16);
    }
    *(unsigned int*)&X[r*XPAD + 2*cp]       = sv;
    *(unsigned int*)&X[r*XPAD + 128 + 2*cp] = pv;
  }
  __syncthreads();

  int wave = tid >> 6, lane = tid & 63;
  int wr0 = wave * 16;
  int m = lane & 15, quad = lane >> 4;

  f32x4 acc[8];
  #pragma unroll
  for (int t = 0; t < 8; t++) acc[t] = (f32x4){0.f, 0.f, 0.f, 0.f};

  const unsigned short* arow = &X[(wr0 + m)*XPAD + quad*8];
  #pragma unroll
  for (int ks = 0; ks < 8; ks++){
    bf16x8 a = *(const bf16x8*)(arow + ks*32);
    #pragma unroll
    for (int t = 0; t < 8; t++){
      bf16x8 b = *(const bf16x8*)&Wf[((ks*8 + t)*64 + lane)*8];
      acc[t] = __builtin_amdgcn_mfma_f32_16x16x32_bf16(a, b, acc[t], 0, 0, 0);
    }
  }

  unsigned short* ego16 = (unsigned short*)egob;
  #pragma unroll
  for (int t = 0; t < 8; t++){
    int col = t*16 + m;
    float bb = b1[col] + b2[col];
    #pragma unroll
    for (int r = 0; r < 4; r++){
      int row = rows_l[wr0 + quad*4 + r];
      if (row >= 0){
        float v = acc[t][r] + bb;
        v = v > 0.f ? v : NEG_SLOPE*v;
        ego16[(size_t)row*D + col] = f2bf(v);
      }
    }
  }
}

// Per-sample dot contributions of the current block (bf16 base).
__global__ __launch_bounds__(256) void score_kernel(const unsigned int* __restrict__ egob, const int* __restrict__ user,
                                                    const int* __restrict__ pos, const int* __restrict__ neg,
                                                    float* __restrict__ pacc, float* __restrict__ nacc,
                                                    int B, int U, int normalize){
  int w = (blockIdx.x*256 + threadIdx.x) >> 6;
  int lane = threadIdx.x & 63;
  if (w >= B) return;
  size_t ur = (size_t)user[w] * 64;
  size_t pr = ((size_t)U + pos[w]) * 64;
  size_t nr = ((size_t)U + neg[w]) * 64;
  unsigned int ub = egob[ur + lane], pb = egob[pr + lane], nb = egob[nr + lane];
  float ux = bf_lo(ub), uy = bf_hi(ub);
  float px = bf_lo(pb), py = bf_hi(pb);
  float nx = bf_lo(nb), ny = bf_hi(nb);
  float dup = ux*px + uy*py;
  float dun = ux*nx + uy*ny;
  float nu  = ux*ux + uy*uy;
  float np  = px*px + py*py;
  float nn  = nx*nx + ny*ny;
  dup = wave_red(dup); dun = wave_red(dun);
  nu = wave_red(nu); np = wave_red(np); nn = wave_red(nn);
  if (lane == 0){
    if (normalize){
      float inu = 1.f / fmaxf(sqrtf(nu), NORM_EPS);
      float inp = 1.f / fmaxf(sqrtf(np), NORM_EPS);
      float inn = 1.f / fmaxf(sqrtf(nn), NORM_EPS);
      pacc[w] += dup * inu * inp;
      nacc[w] += dun * inu * inn;
    } else {
      pacc[w] += dup;
      nacc[w] += dun;
    }
  }
}

__global__ __launch_bounds__(256) void reg_kernel(const float* __restrict__ item, const int* __restrict__ pos,
                                                  const int* __restrict__ neg, float* __restrict__ reg_out, int B){
  int w = (blockIdx.x*256 + threadIdx.x) >> 6;
  int lane = threadIdx.x & 63;
  if (w >= B) return;
  const float2* it = (const float2*)item;
  float2 pv = it[(size_t)pos[w]*64 + lane];
  float2 nv = it[(size_t)neg[w]*64 + lane];
  float v = pv.x*pv.x + pv.y*pv.y + nv.x*nv.x + nv.y*nv.y;
  v = wave_red(v);
  if (lane == 0) atomicAdd(reg_out, v);
}

__global__ __launch_bounds__(256) void final_kernel(const float* __restrict__ pacc, const float* __restrict__ nacc,
                                                    const float* __restrict__ reg_sum, float* __restrict__ out, int B){
  __shared__ float red[256];
  float s = 0.f;
  for (int i = threadIdx.x; i < B; i += 256){
    float x = nacc[i] - pacc[i];
    s += (x > 0.f) ? x + log1pf(expf(-x)) : log1pf(expf(x));   // softplus, stable
  }
  red[threadIdx.x] = s; __syncthreads();
  for (int o = 128; o > 0; o >>= 1){
    if (threadIdx.x < o) red[threadIdx.x] += red[threadIdx.x + o];
    __syncthreads();
  }
  if (threadIdx.x == 0){
    out[0] = red[0] / (float)B;
    out[1] = REG_LAMBDA * 0.5f * reg_sum[0] / (float)B;
  }
}

extern "C" void kernel_launch(void* const* d_in, const int* in_sizes, int n_in,
                              void* d_out, int out_size, void* d_ws, size_t ws_size,
                              hipStream_t stream) {
  const int*   user = (const int*)d_in[0];
  const int*   pos  = (const int*)d_in[1];
  const int*   neg  = (const int*)d_in[2];
  const int*   erow = (const int*)d_in[3];
  const int*   ecol = (const int*)d_in[4];
  const float* eval = (const float*)d_in[5];
  const float* uemb = (const float*)d_in[6];
  const float* iemb = (const float*)d_in[7];
  const float* Wg   = (const float*)d_in[8];
  const float* bg   = (const float*)d_in[9];
  const float* Wb   = (const float*)d_in[10];
  const float* bb   = (const float*)d_in[11];

  int B   = in_sizes[0];
  int NNZ = in_sizes[3];
  int U   = in_sizes[6] / D;
  int I   = in_sizes[7] / D;
  int N   = U + I;
  int L   = in_sizes[9] / D;
  int nbk = (N + RPB - 1) >> RPB_SHIFT;
  int Tc  = (N + (1 << TCSH) - 1) >> TCSH;

  char* wsp = (char*)d_ws;
  auto alloc = [&](size_t bytes) -> char* {
    char* p = wsp; wsp += (bytes + 255) & ~(size_t)255; return p;
  };
  size_t side_bytes = (size_t)N * D * 2;
  size_t ebuf_bytes = (size_t)NNZ * 8;
  unsigned int*  sideb  = (unsigned int*)alloc(side_bytes > ebuf_bytes ? side_bytes : ebuf_bytes);
  unsigned int*  egob   = (unsigned int*)alloc((size_t)N * D * 2);     // bf16 ego, pair-packed
  unsigned short* egof8 = (unsigned short*)alloc((size_t)N * D);       // fp8-e4m3 ego, pair-packed
  int2*          ep     = (int2*) alloc((size_t)NNZ * 8);              // CSR edges (byte-off, val)
  unsigned short* Wf    = (unsigned short*)alloc((size_t)L * 256 * D * 2);
  int*           rowptr = (int*)  alloc((size_t)(N + 1) * 4);
  int*           bcnt   = (int*)  alloc((size_t)MAXB * 4);
  int*           bbase  = (int*)  alloc((size_t)(MAXB + 1) * 4);
  int*           bcur   = (int*)  alloc((size_t)MAXB * 4);
  int*           lcnt   = (int*)  alloc(256 * 4);
  int*           lcur   = (int*)  alloc(256 * 4);
  int*           rowperm= (int*)  alloc((size_t)N * 4);
  float*         pacc   = (float*)alloc((size_t)B * 4);
  float*         nacc   = (float*)alloc((size_t)B * 4);
  float*         regs   = (float*)alloc(256);
  int2*          ebuf   = (int2*)sideb;   // staging alias (build phase only)

  hipMemsetAsync(bcnt, 0, (size_t)nbk * 4, stream);
  hipMemsetAsync(lcnt, 0, 256 * 4, stream);
  hipMemsetAsync(pacc, 0, (size_t)B * 4, stream);
  hipMemsetAsync(nacc, 0, (size_t)B * 4, stream);
  hipMemsetAsync(regs, 0, 4, stream);

  toq_kernel<<<(U*64 + 255) / 256, 256, 0, stream>>>(uemb, egob, egof8, U*64);
  toq_kernel<<<(I*64 + 255) / 256, 256, 0, stream>>>(iemb, egob + (size_t)U*64, egof8 + (size_t)U*64, I*64);
  wconv_kernel<<<(L*256*D + 255) / 256, 256, 0, stream>>>(Wg, Wb, Wf, L);

  // Bucketed CSR build (edges within a row ordered by col-tile)
  bhist_kernel<<<2048, 256, 0, stream>>>(erow, bcnt, NNZ, nbk);
  bscan_kernel<<<1, 1024, 0, stream>>>(bcnt, bbase, bcur, rowptr, nbk, NNZ, N);
  bscatter_kernel<<<(NNZ + CHUNK - 1) / CHUNK, 256, 0, stream>>>(erow, ecol, eval, bcur, ebuf, NNZ, nbk);
  fscatter_kernel<<<nbk, 256, 0, stream>>>(ebuf, bbase, ep, rowptr, Tc, N);

  // Row permutation: descending length (spmm block-retirement balance)
  lhist_kernel<<<1024, 256, 0, stream>>>(rowptr, lcnt, N);
  lscan_kernel<<<1, 256, 0, stream>>>(lcnt, lcur);
  lscatter_kernel<<<128, 256, 0, stream>>>(rowptr, lcur, rowperm, N);

  // Block 0 (raw embeddings, un-normalized)
  score_kernel<<<(B + 3) / 4, 256, 0, stream>>>(egob, user, pos, neg, pacc, nacc, B, U, 0);

  int sampledN = 3 * B;
  bool use_samp = (sampledN < N);

  for (int l = 0; l < L; l++){
    if (use_samp && l == L - 1){
      // Final layer: only rows read by the loss (user | U+pos | U+neg).
      spmm_samp_kernel<<<(sampledN + 3) / 4, 256, 0, stream>>>(
          rowptr, ep, (const unsigned char*)egof8, sideb, user, pos, neg, B, U);
      transform_samp_kernel<<<(sampledN + 63) / 64, 256, 0, stream>>>(
          sideb, egob, Wf + (size_t)l * 256 * D,
          bg + (size_t)l * D, bb + (size_t)l * D, user, pos, neg, B, U);
    } else {
      spmm_kernel<<<(N + 3) / 4, 256, 0, stream>>>(rowptr, ep, (const unsigned char*)egof8, sideb, rowperm, N);
      transform_kernel<<<(N + 63) / 64, 256, 0, stream>>>(
          sideb, egob, (unsigned char*)egof8, Wf + (size_t)l * 256 * D,
          bg + (size_t)l * D, bb + (size_t)l * D, N);
    }
    score_kernel<<<(B + 3) / 4, 256, 0, stream>>>(egob, user, pos, neg, pacc, nacc, B, U, 1);
  }

  reg_kernel<<<(B + 3) / 4, 256, 0, stream>>>(iemb, pos, neg, regs, B);
  final_kernel<<<1, 256, 0, stream>>>(pacc, nacc, regs, (float*)d_out, B);
}

// Round 10
// 729.308 us; speedup vs baseline: 1.4373x; 1.0732x over previous
//
#include <hip/hip_runtime.h>
#include <math.h>

#define D 128
#define NEG_SLOPE 0.2f
#define REG_LAMBDA 1e-4f
#define NORM_EPS 1e-12f

#define RPB 256          // rows per coarse bucket
#define RPB_SHIFT 8
#define MAXB 1024        // max coarse buckets (N <= 262144)
#define CHUNK 2048       // edges per bscatter block (33 KB LDS -> 4 blocks/CU)
#define TCSH 14          // 16384 cols per col-tile (for within-row edge ordering)
#define KEYMAX 4096      // 256 rows * Tc ; Tc<=16 -> N <= 262144

#define XPAD 264         // padded LDS row stride in bf16 elems (256 + 8)

using bf16x8 = __attribute__((ext_vector_type(8))) short;
using f32x4  = __attribute__((ext_vector_type(4))) float;
using f32x2  = __attribute__((ext_vector_type(2))) float;

__device__ __forceinline__ float wave_red(float v){
  #pragma unroll
  for (int o = 32; o > 0; o >>= 1) v += __shfl_xor(v, o, 64);
  return v;
}

__device__ __forceinline__ unsigned short f2bf(float f){
  unsigned int u = __float_as_uint(f);
  unsigned int r = (u + 0x7fffu + ((u >> 16) & 1u)) >> 16;  // RNE
  return (unsigned short)r;
}
__device__ __forceinline__ float bf_lo(unsigned int x){ return __uint_as_float(x << 16); }
__device__ __forceinline__ float bf_hi(unsigned int x){ return __uint_as_float(x & 0xffff0000u); }

// packed 2xf32 FMA (VOP3P): d = a*b + c on both halves
__device__ __forceinline__ f32x2 pk_fma(f32x2 a, f32x2 b, f32x2 c){
  f32x2 d;
  asm("v_pk_fma_f32 %0, %1, %2, %3" : "=v"(d) : "v"(a), "v"(b), "v"(c));
  return d;
}
// hardware 2xf32 -> packed bf16 (RNE) — bit-matches f2bf (verified via spmm, absmax 0)
__device__ __forceinline__ unsigned int pk_bf16(float lo, float hi){
  unsigned int d;
  asm("v_cvt_pk_bf16_f32 %0, %1, %2" : "=v"(d) : "v"(lo), "v"(hi));
  return d;
}

// fp32 pair -> (bf16 pair packed in uint, fp8-e4m3 pair packed in ushort).
// Single launch for user+item tables (branch on the U boundary).
__global__ __launch_bounds__(256) void toq_kernel(const float* __restrict__ usrc, const float* __restrict__ isrc,
                                                  unsigned int* __restrict__ dstb,
                                                  unsigned short* __restrict__ dst8, int upairs, int totpairs){
  int i = blockIdx.x*256 + threadIdx.x;
  if (i >= totpairs) return;
  const float* src = (i < upairs) ? usrc : isrc;
  int j = (i < upairs) ? i : i - upairs;
  float2 v = ((const float2*)src)[j];
  dstb[i] = (unsigned int)f2bf(v.x) | ((unsigned int)f2bf(v.y) << 16);
  int p = __builtin_amdgcn_cvt_pk_fp8_f32(v.x, v.y, 0, false);
  dst8[i] = (unsigned short)(p & 0xffff);
}

// W_gcn/W_bi (fp32 row-major) -> per-layer MFMA B-fragment order bf16.
__global__ __launch_bounds__(256) void wconv_kernel(const float* __restrict__ Wg, const float* __restrict__ Wb,
                                                    unsigned short* __restrict__ Wf, int L){
  int idx = blockIdx.x*256 + threadIdx.x;
  int total = L * 256 * D;
  if (idx >= total) return;
  int l = idx >> 15;
  int rem = idx & 32767;
  int k = rem >> 7;
  int n = rem & 127;
  float v = (k < 128) ? Wg[((size_t)l*128 + k)*D + n] : Wb[((size_t)l*128 + (k-128))*D + n];
  int ks = k >> 5, quad = (k >> 3) & 3, j = k & 7;
  int t = n >> 4, ln = (quad << 4) | (n & 15);
  Wf[(size_t)l*32768 + (((ks*8 + t)*64 + ln)*8 + j)] = f2bf(v);
}

// K1: coarse bucket histogram, LDS-aggregated, loads batched 4-wide
__global__ __launch_bounds__(256) void bhist_kernel(const int* __restrict__ erow, int* __restrict__ bcnt, int nnz, int nbk){
  __shared__ int h[MAXB];
  for (int i = threadIdx.x; i < nbk; i += 256) h[i] = 0;
  __syncthreads();
  int stride = gridDim.x * 256;
  int e = blockIdx.x*256 + threadIdx.x;
  for (; e + 3*stride < nnz; e += 4*stride){
    int r0 = erow[e], r1 = erow[e+stride], r2 = erow[e+2*stride], r3 = erow[e+3*stride];
    atomicAdd(&h[r0 >> RPB_SHIFT], 1);
    atomicAdd(&h[r1 >> RPB_SHIFT], 1);
    atomicAdd(&h[r2 >> RPB_SHIFT], 1);
    atomicAdd(&h[r3 >> RPB_SHIFT], 1);
  }
  for (; e < nnz; e += stride)
    atomicAdd(&h[erow[e] >> RPB_SHIFT], 1);
  __syncthreads();
  for (int i = threadIdx.x; i < nbk; i += 256){
    int c = h[i];
    if (c) atomicAdd(&bcnt[i], c);
  }
}

// K2: exclusive scan of bucket counts (single block)
__global__ __launch_bounds__(1024) void bscan_kernel(const int* __restrict__ bcnt, int* __restrict__ bbase,
                                                     int* __restrict__ bcur, int* __restrict__ rowptr,
                                                     int nbk, int nnz, int n){
  __shared__ int tmp[1024];
  int t = threadIdx.x;
  int v = (t < nbk) ? bcnt[t] : 0;
  tmp[t] = v; __syncthreads();
  #pragma unroll
  for (int off = 1; off < 1024; off <<= 1){
    int a = (t >= off) ? tmp[t-off] : 0; __syncthreads();
    tmp[t] += a; __syncthreads();
  }
  if (t < nbk){ int b = tmp[t] - v; bbase[t] = b; bcur[t] = b; }
  if (t == 0){ bbase[nbk] = nnz; rowptr[n] = nnz; }
}

// K3: coarse scatter. Block sorts a CHUNK of edges by bucket in LDS, reserves
// global ranges, writes coalesced runs. ebuf.x = col | (row_low8 << 20).
__global__ __launch_bounds__(256) void bscatter_kernel(const int* __restrict__ erow, const int* __restrict__ ecol,
                                                       const float* __restrict__ eval, int* __restrict__ bcur,
                                                       int2* __restrict__ ebuf, int nnz, int nbk){
  __shared__ int2 ls[CHUNK];
  __shared__ int gdst[CHUNK];
  __shared__ int h[MAXB];
  __shared__ int hx[MAXB];
  __shared__ int tmp[256];
  int tid = threadIdx.x;
  int base = blockIdx.x * CHUNK;
  int cn = min(CHUNK, nnz - base);
  bool full = (cn == CHUNK);
  for (int i = tid; i < nbk; i += 256) h[i] = 0;
  __syncthreads();

  int r[8];
  if (full){
    #pragma unroll
    for (int k = 0; k < 8; k++) r[k] = erow[base + tid + 256*k];
    #pragma unroll
    for (int k = 0; k < 8; k++) atomicAdd(&h[r[k] >> RPB_SHIFT], 1);
  } else {
    #pragma unroll
    for (int k = 0; k < 8; k++){
      int i = tid + 256*k;
      r[k] = (i < cn) ? erow[base + i] : -1;
    }
    #pragma unroll
    for (int k = 0; k < 8; k++)
      if (r[k] >= 0) atomicAdd(&h[r[k] >> RPB_SHIFT], 1);
  }
  __syncthreads();

  int b0 = tid*4;
  int c0=0,c1=0,c2=0,c3=0;
  if (b0 < nbk){
    c0 = h[b0];
    if (b0+1 < nbk) c1 = h[b0+1];
    if (b0+2 < nbk) c2 = h[b0+2];
    if (b0+3 < nbk) c3 = h[b0+3];
  }
  int tsum = c0+c1+c2+c3;
  tmp[tid] = tsum; __syncthreads();
  #pragma unroll
  for (int off = 1; off < 256; off <<= 1){
    int a = (tid >= off) ? tmp[tid-off] : 0; __syncthreads();
    tmp[tid] += a; __syncthreads();
  }
  int tbase = tmp[tid] - tsum;
  if (b0 < nbk){
    hx[b0] = tbase;
    if (b0+1 < nbk) hx[b0+1] = tbase + c0;
    if (b0+2 < nbk) hx[b0+2] = tbase + c0 + c1;
    if (b0+3 < nbk) hx[b0+3] = tbase + c0 + c1 + c2;
  }
  __syncthreads();
  for (int i = tid; i < nbk; i += 256){
    int c = h[i];
    if (c > 0){
      int gb = atomicAdd(&bcur[i], c);
      h[i] = gb - hx[i];
    }
  }
  __syncthreads();

  if (full){
    int c[8]; float v[8];
    #pragma unroll
    for (int k = 0; k < 8; k++) c[k] = ecol[base + tid + 256*k];
    #pragma unroll
    for (int k = 0; k < 8; k++) v[k] = eval[base + tid + 256*k];
    #pragma unroll
    for (int k = 0; k < 8; k++){
      int rr = r[k];
      int b = rr >> RPB_SHIFT;
      int x = c[k] | ((rr & (RPB-1)) << 20);
      int lpos = atomicAdd(&hx[b], 1);
      ls[lpos] = make_int2(x, __float_as_int(v[k]));
      gdst[lpos] = h[b] + lpos;
    }
  } else {
    for (int i = tid; i < cn; i += 256){
      int rr = erow[base+i];
      int b = rr >> RPB_SHIFT;
      int x = ecol[base+i] | ((rr & (RPB-1)) << 20);
      int lpos = atomicAdd(&hx[b], 1);
      ls[lpos] = make_int2(x, __float_as_int(eval[base+i]));
      gdst[lpos] = h[b] + lpos;
    }
  }
  __syncthreads();
  if (full){
    #pragma unroll
    for (int k = 0; k < 8; k++){
      int i = tid + 256*k;
      ebuf[gdst[i]] = ls[i];
    }
  } else {
    for (int i = tid; i < cn; i += 256)
      ebuf[gdst[i]] = ls[i];
  }
}

// K4: one block per coarse bucket. Counting sort by key = (row_low8, col-tile)
// -> rowptr + final CSR (edges within a row ordered by col-tile).
// ep.x = byte offset into fp8 table (col * 128). Both passes batched 8-wide.
__global__ __launch_bounds__(256) void fscatter_kernel(const int2* __restrict__ ebuf, const int* __restrict__ bbase,
                                                       int2* __restrict__ ep, int* __restrict__ rowptr,
                                                       int Tc, int n){
  __shared__ int h[KEYMAX];
  __shared__ int tsum[256];
  int b = blockIdx.x;
  int tid = threadIdx.x;
  int s = bbase[b], e = bbase[b+1];
  int row0 = b << RPB_SHIFT;
  int nk = 256 * Tc;
  for (int i = tid; i < nk; i += 256) h[i] = 0;
  __syncthreads();

  int i = s + tid;
  for (; i + 256*7 < e; i += 256*8){
    int x[8];
    #pragma unroll
    for (int k = 0; k < 8; k++) x[k] = ebuf[i + 256*k].x;
    #pragma unroll
    for (int k = 0; k < 8; k++){
      int key = ((x[k] >> 20) & 255) * Tc + ((x[k] & 0xFFFFF) >> TCSH);
      atomicAdd(&h[key], 1);
    }
  }
  for (; i < e; i += 256){
    int x = ebuf[i].x;
    int key = ((x >> 20) & 255) * Tc + ((x & 0xFFFFF) >> TCSH);
    atomicAdd(&h[key], 1);
  }
  __syncthreads();
  // exclusive scan: thread tid owns keys of row tid (segment of Tc)
  int my0 = tid * Tc;
  int run = 0;
  for (int j = 0; j < Tc; j++){
    int c = h[my0 + j]; h[my0 + j] = run; run += c;
  }
  tsum[tid] = run; __syncthreads();
  #pragma unroll
  for (int off = 1; off < 256; off <<= 1){
    int a = (tid >= off) ? tsum[tid-off] : 0; __syncthreads();
    tsum[tid] += a; __syncthreads();
  }
  int bt = tsum[tid] - run;
  for (int j = 0; j < Tc; j++) h[my0 + j] += bt;
  __syncthreads();
  if (row0 + tid < n) rowptr[row0 + tid] = s + h[my0];
  __syncthreads();

  i = s + tid;
  for (; i + 256*7 < e; i += 256*8){
    int2 E[8];
    #pragma unroll
    for (int k = 0; k < 8; k++) E[k] = ebuf[i + 256*k];
    #pragma unroll
    for (int k = 0; k < 8; k++){
      int x = E[k].x;
      int col = x & 0xFFFFF;
      int key = ((x >> 20) & 255) * Tc + (col >> TCSH);
      int p = atomicAdd(&h[key], 1);
      ep[s + p] = make_int2(col << 7, E[k].y);   // byte offset
    }
  }
  for (; i < e; i += 256){
    int2 E = ebuf[i];
    int x = E.x;
    int col = x & 0xFFFFF;
    int key = ((x >> 20) & 255) * Tc + (col >> TCSH);
    int p = atomicAdd(&h[key], 1);
    ep[s + p] = make_int2(col << 7, E.y);
  }
}

// Shared per-row SpMM body: side[row] = bf16( sum_e val_e * ego_fp8[off_e] ).
// One wave per row. Lane i reads 8 B of row E[i>>4] at byte (i&15)*8 -> 64
// lanes span 4 random 128-B rows per VMEM instr. Steady state: 32-edge
// iterations (8 gathers in flight, no clamp/select chain); remainder uses
// the clamped 16-edge path. FMAs packed (v_pk_fma_f32); gather offset is
// E.x | (seg*8) (ep.x = col<<7, low 7 bits free).
// NOTE (R1/R2/R3/R6/R9 evidence): this kernel is at its structural floor —
// per-CU MSHR saturation on ~230 MB of irreducible random L2-miss traffic.
// Occupancy tweaks, per-wave MLP, persistence, and length-sorting are all
// neutral-to-negative. Do not touch.
__device__ __forceinline__ void spmm_row_body(int row, int lane,
                                              const int* __restrict__ rowptr, const int2* __restrict__ ep,
                                              const unsigned char* __restrict__ egof8,
                                              unsigned int* __restrict__ sideb){
  int s = rowptr[row], e = rowptr[row+1];
  int sub  = lane >> 4;     // which edge of the quad
  int half = lane & 15;     // which 8-byte segment of the 128-B row
  int half8 = half << 3;

  f32x2 acc2[4];
  #pragma unroll
  for (int j = 0; j < 4; j++) acc2[j] = (f32x2){0.f, 0.f};

  int base = s;
  for (; base + 32 <= e; base += 32){
    int2 E[8]; uint2 X[8];
    #pragma unroll
    for (int k = 0; k < 8; k++) E[k] = ep[base + 4*k + sub];
    #pragma unroll
    for (int k = 0; k < 8; k++)
      X[k] = *(const uint2*)(egof8 + (size_t)(unsigned)(E[k].x | half8));
    #pragma unroll
    for (int k = 0; k < 8; k++){
      float v = __int_as_float(E[k].y);
      f32x2 vv = (f32x2){v, v};
      acc2[0] = pk_fma(vv, __builtin_amdgcn_cvt_pk_f32_fp8((int)X[k].x, false), acc2[0]);
      acc2[1] = pk_fma(vv, __builtin_amdgcn_cvt_pk_f32_fp8((int)X[k].x, true ), acc2[1]);
      acc2[2] = pk_fma(vv, __builtin_amdgcn_cvt_pk_f32_fp8((int)X[k].y, false), acc2[2]);
      acc2[3] = pk_fma(vv, __builtin_amdgcn_cvt_pk_f32_fp8((int)X[k].y, true ), acc2[3]);
    }
  }
  for (; base < e; base += 16){
    int2 E[4]; uint2 X[4];
    #pragma unroll
    for (int k = 0; k < 4; k++){
      int idx = base + 4*k + sub;
      idx = idx < e ? idx : e - 1;
      E[k] = ep[idx];
    }
    #pragma unroll
    for (int k = 0; k < 4; k++)
      X[k] = *(const uint2*)(egof8 + (size_t)(unsigned)(E[k].x | half8));
    #pragma unroll
    for (int k = 0; k < 4; k++){
      float v = (base + 4*k + sub < e) ? __int_as_float(E[k].y) : 0.f;
      f32x2 vv = (f32x2){v, v};
      acc2[0] = pk_fma(vv, __builtin_amdgcn_cvt_pk_f32_fp8((int)X[k].x, false), acc2[0]);
      acc2[1] = pk_fma(vv, __builtin_amdgcn_cvt_pk_f32_fp8((int)X[k].x, true ), acc2[1]);
      acc2[2] = pk_fma(vv, __builtin_amdgcn_cvt_pk_f32_fp8((int)X[k].y, false), acc2[2]);
      acc2[3] = pk_fma(vv, __builtin_amdgcn_cvt_pk_f32_fp8((int)X[k].y, true ), acc2[3]);
    }
  }
  #pragma unroll
  for (int j = 0; j < 4; j++){
    acc2[j][0] += __shfl_xor(acc2[j][0], 16, 64);
    acc2[j][1] += __shfl_xor(acc2[j][1], 16, 64);
    acc2[j][0] += __shfl_xor(acc2[j][0], 32, 64);
    acc2[j][1] += __shfl_xor(acc2[j][1], 32, 64);
  }
  if (lane < 16){
    unsigned int o0 = pk_bf16(acc2[0][0], acc2[0][1]);
    unsigned int o1 = pk_bf16(acc2[1][0], acc2[1][1]);
    unsigned int o2 = pk_bf16(acc2[2][0], acc2[2][1]);
    unsigned int o3 = pk_bf16(acc2[3][0], acc2[3][1]);
    *(uint4*)(sideb + (size_t)row*64 + half*4) = make_uint4(o0, o1, o2, o3);
  }
}

// Full-graph SpMM: wave w -> row w.
__global__ __launch_bounds__(256) void spmm_kernel(const int* __restrict__ rowptr, const int2* __restrict__ ep,
                                                   const unsigned char* __restrict__ egof8,
                                                   unsigned int* __restrict__ sideb, int n){
  int w = (blockIdx.x*256 + threadIdx.x) >> 6;
  int lane = threadIdx.x & 63;
  if (w >= n) return;
  spmm_row_body(w, lane, rowptr, ep, egof8, sideb);
}

// sample slot -> graph row (user | U+pos | U+neg)
__device__ __forceinline__ int samp_row(int slot, const int* __restrict__ user, const int* __restrict__ pos,
                                        const int* __restrict__ neg, int B, int U){
  if (slot < B)   return user[slot];
  if (slot < 2*B) return U + pos[slot - B];
  return U + neg[slot - 2*B];
}

// Last-layer SpMM restricted to sample rows. Duplicate slots compute the
// identical row -> byte-identical concurrent writes (benign).
__global__ __launch_bounds__(256) void spmm_samp_kernel(const int* __restrict__ rowptr, const int2* __restrict__ ep,
                                                        const unsigned char* __restrict__ egof8,
                                                        unsigned int* __restrict__ sideb,
                                                        const int* __restrict__ user, const int* __restrict__ pos,
                                                        const int* __restrict__ neg, int B, int U){
  int w = (blockIdx.x*256 + threadIdx.x) >> 6;
  int lane = threadIdx.x & 63;
  if (w >= 3*B) return;
  int row = samp_row(w, user, pos, neg, B, U);
  spmm_row_body(row, lane, rowptr, ep, egof8, sideb);
}

// MFMA transform: egob[r] = bf16(leaky( [side | ego.*side] @ Wc + b ));
// also writes the fp8 shadow for the next layer's spmm gather.
// Staging vectorized to uint4 (16 B/lane, G13) + hw pk_bf16 for ego.*side.
__global__ __launch_bounds__(256, 4) void transform_kernel(const unsigned int* __restrict__ sideb,
                                                           unsigned int* __restrict__ egob,
                                                           unsigned char* __restrict__ egof8,
                                                           const unsigned short* __restrict__ Wf,
                                                           const float* __restrict__ b1, const float* __restrict__ b2,
                                                           int n){
  __shared__ __align__(16) unsigned short X[64 * XPAD];   // 33 KB
  int row0 = blockIdx.x * 64;
  int tid = threadIdx.x;
  for (int idx = tid; idx < 64*16; idx += 256){
    int r = idx >> 4, c4 = idx & 15;   // which 16-B chunk of the 256-B row
    int row = row0 + r;
    uint4 sv = make_uint4(0u,0u,0u,0u);
    uint4 pv = make_uint4(0u,0u,0u,0u);
    if (row < n){
      uint4 s4 = *(const uint4*)(sideb + (size_t)row*64 + c4*4);
      uint4 e4 = *(const uint4*)(egob  + (size_t)row*64 + c4*4);
      sv = s4;
      pv.x = pk_bf16(bf_lo(s4.x)*bf_lo(e4.x), bf_hi(s4.x)*bf_hi(e4.x));
      pv.y = pk_bf16(bf_lo(s4.y)*bf_lo(e4.y), bf_hi(s4.y)*bf_hi(e4.y));
      pv.z = pk_bf16(bf_lo(s4.z)*bf_lo(e4.z), bf_hi(s4.z)*bf_hi(e4.z));
      pv.w = pk_bf16(bf_lo(s4.w)*bf_lo(e4.w), bf_hi(s4.w)*bf_hi(e4.w));
    }
    *(uint4*)&X[r*XPAD + 8*c4]       = sv;   // byte off = 528r + 16c4 (16-B aligned)
    *(uint4*)&X[r*XPAD + 128 + 8*c4] = pv;
  }
  __syncthreads();

  int wave = tid >> 6, lane = tid & 63;
  int wr0 = wave * 16;
  int m = lane & 15, quad = lane >> 4;

  f32x4 acc[8];
  #pragma unroll
  for (int t = 0; t < 8; t++) acc[t] = (f32x4){0.f, 0.f, 0.f, 0.f};

  const unsigned short* arow = &X[(wr0 + m)*XPAD + quad*8];
  #pragma unroll
  for (int ks = 0; ks < 8; ks++){
    bf16x8 a = *(const bf16x8*)(arow + ks*32);
    #pragma unroll
    for (int t = 0; t < 8; t++){
      bf16x8 b = *(const bf16x8*)&Wf[((ks*8 + t)*64 + lane)*8];
      acc[t] = __builtin_amdgcn_mfma_f32_16x16x32_bf16(a, b, acc[t], 0, 0, 0);
    }
  }

  unsigned short* ego16 = (unsigned short*)egob;
  #pragma unroll
  for (int t = 0; t < 8; t++){
    int col = t*16 + m;
    float bb = b1[col] + b2[col];
    #pragma unroll
    for (int r = 0; r < 4; r++){
      int row = row0 + wr0 + quad*4 + r;
      if (row < n){
        float v = acc[t][r] + bb;
        v = v > 0.f ? v : NEG_SLOPE*v;
        ego16[(size_t)row*D + col] = f2bf(v);
        egof8[(size_t)row*D + col] =
            (unsigned char)(__builtin_amdgcn_cvt_pk_fp8_f32(v, v, 0, false) & 0xff);
      }
    }
  }
}

// Last-layer transform restricted to sample rows (no fp8 shadow: nothing
// reads it after the final layer). Duplicate rows -> identical writes.
__global__ __launch_bounds__(256, 4) void transform_samp_kernel(const unsigned int* __restrict__ sideb,
                                                                unsigned int* __restrict__ egob,
                                                                const unsigned short* __restrict__ Wf,
                                                                const float* __restrict__ b1, const float* __restrict__ b2,
                                                                const int* __restrict__ user, const int* __restrict__ pos,
                                                                const int* __restrict__ neg, int B, int U){
  __shared__ __align__(16) unsigned short X[64 * XPAD];   // 33 KB
  __shared__ int rows_l[64];
  int slot0 = blockIdx.x * 64;
  int tid = threadIdx.x;
  int total = 3*B;
  if (tid < 64){
    int slot = slot0 + tid;
    rows_l[tid] = (slot < total) ? samp_row(slot, user, pos, neg, B, U) : -1;
  }
  __syncthreads();
  for (int idx = tid; idx < 64*16; idx += 256){
    int r = idx >> 4, c4 = idx & 15;
    int row = rows_l[r];
    uint4 sv = make_uint4(0u,0u,0u,0u);
    uint4 pv = make_uint4(0u,0u,0u,0u);
    if (row >= 0){
      uint4 s4 = *(const uint4*)(sideb + (size_t)row*64 + c4*4);
      uint4 e4 = *(const uint4*)(egob  + (size_t)row*64 + c4*4);
      sv = s4;
      pv.x = pk_bf16(bf_lo(s4.x)*bf_lo(e4.x), bf_hi(s4.x)*bf_hi(e4.x));
      pv.y = pk_bf16(bf_lo(s4.y)*bf_lo(e4.y), bf_hi(s4.y)*bf_hi(e4.y));
      pv.z = pk_bf16(bf_lo(s4.z)*bf_lo(e4.z), bf_hi(s4.z)*bf_hi(e4.z));
      pv.w = pk_bf16(bf_lo(s4.w)*bf_lo(e4.w), bf_hi(s4.w)*bf_hi(e4.w));
    }
    *(uint4*)&X[r*XPAD + 8*c4]       = sv;
    *(uint4*)&X[r*XPAD + 128 + 8*c4] = pv;
  }
  __syncthreads();

  int wave = tid >> 6, lane = tid & 63;
  int wr0 = wave * 16;
  int m = lane & 15, quad = lane >> 4;

  f32x4 acc[8];
  #pragma unroll
  for (int t = 0; t < 8; t++) acc[t] = (f32x4){0.f, 0.f, 0.f, 0.f};

  const unsigned short* arow = &X[(wr0 + m)*XPAD + quad*8];
  #pragma unroll
  for (int ks = 0; ks < 8; ks++){
    bf16x8 a = *(const bf16x8*)(arow + ks*32);
    #pragma unroll
    for (int t = 0; t < 8; t++){
      bf16x8 b = *(const bf16x8*)&Wf[((ks*8 + t)*64 + lane)*8];
      acc[t] = __builtin_amdgcn_mfma_f32_16x16x32_bf16(a, b, acc[t], 0, 0, 0);
    }
  }

  unsigned short* ego16 = (unsigned short*)egob;
  #pragma unroll
  for (int t = 0; t < 8; t++){
    int col = t*16 + m;
    float bb = b1[col] + b2[col];
    #pragma unroll
    for (int r = 0; r < 4; r++){
      int row = rows_l[wr0 + quad*4 + r];
      if (row >= 0){
        float v = acc[t][r] + bb;
        v = v > 0.f ? v : NEG_SLOPE*v;
        ego16[(size_t)row*D + col] = f2bf(v);
      }
    }
  }
}

// Per-sample dot contributions of the current block (bf16 base).
__global__ __launch_bounds__(256) void score_kernel(const unsigned int* __restrict__ egob, const int* __restrict__ user,
                                                    const int* __restrict__ pos, const int* __restrict__ neg,
                                                    float* __restrict__ pacc, float* __restrict__ nacc,
                                                    int B, int U, int normalize){
  int w = (blockIdx.x*256 + threadIdx.x) >> 6;
  int lane = threadIdx.x & 63;
  if (w >= B) return;
  size_t ur = (size_t)user[w] * 64;
  size_t pr = ((size_t)U + pos[w]) * 64;
  size_t nr = ((size_t)U + neg[w]) * 64;
  unsigned int ub = egob[ur + lane], pb = egob[pr + lane], nb = egob[nr + lane];
  float ux = bf_lo(ub), uy = bf_hi(ub);
  float px = bf_lo(pb), py = bf_hi(pb);
  float nx = bf_lo(nb), ny = bf_hi(nb);
  float dup = ux*px + uy*py;
  float dun = ux*nx + uy*ny;
  float nu  = ux*ux + uy*uy;
  float np  = px*px + py*py;
  float nn  = nx*nx + ny*ny;
  dup = wave_red(dup); dun = wave_red(dun);
  nu = wave_red(nu); np = wave_red(np); nn = wave_red(nn);
  if (lane == 0){
    if (normalize){
      float inu = 1.f / fmaxf(sqrtf(nu), NORM_EPS);
      float inp = 1.f / fmaxf(sqrtf(np), NORM_EPS);
      float inn = 1.f / fmaxf(sqrtf(nn), NORM_EPS);
      pacc[w] += dup * inu * inp;
      nacc[w] += dun * inu * inn;
    } else {
      pacc[w] += dup;
      nacc[w] += dun;
    }
  }
}

__global__ __launch_bounds__(256) void reg_kernel(const float* __restrict__ item, const int* __restrict__ pos,
                                                  const int* __restrict__ neg, float* __restrict__ reg_out, int B){
  int w = (blockIdx.x*256 + threadIdx.x) >> 6;
  int lane = threadIdx.x & 63;
  if (w >= B) return;
  const float2* it = (const float2*)item;
  float2 pv = it[(size_t)pos[w]*64 + lane];
  float2 nv = it[(size_t)neg[w]*64 + lane];
  float v = pv.x*pv.x + pv.y*pv.y + nv.x*nv.x + nv.y*nv.y;
  v = wave_red(v);
  if (lane == 0) atomicAdd(reg_out, v);
}

__global__ __launch_bounds__(256) void final_kernel(const float* __restrict__ pacc, const float* __restrict__ nacc,
                                                    const float* __restrict__ reg_sum, float* __restrict__ out, int B){
  __shared__ float red[256];
  float s = 0.f;
  for (int i = threadIdx.x; i < B; i += 256){
    float x = nacc[i] - pacc[i];
    s += (x > 0.f) ? x + log1pf(expf(-x)) : log1pf(expf(x));   // softplus, stable
  }
  red[threadIdx.x] = s; __syncthreads();
  for (int o = 128; o > 0; o >>= 1){
    if (threadIdx.x < o) red[threadIdx.x] += red[threadIdx.x + o];
    __syncthreads();
  }
  if (threadIdx.x == 0){
    out[0] = red[0] / (float)B;
    out[1] = REG_LAMBDA * 0.5f * reg_sum[0] / (float)B;
  }
}

extern "C" void kernel_launch(void* const* d_in, const int* in_sizes, int n_in,
                              void* d_out, int out_size, void* d_ws, size_t ws_size,
                              hipStream_t stream) {
  const int*   user = (const int*)d_in[0];
  const int*   pos  = (const int*)d_in[1];
  const int*   neg  = (const int*)d_in[2];
  const int*   erow = (const int*)d_in[3];
  const int*   ecol = (const int*)d_in[4];
  const float* eval = (const float*)d_in[5];
  const float* uemb = (const float*)d_in[6];
  const float* iemb = (const float*)d_in[7];
  const float* Wg   = (const float*)d_in[8];
  const float* bg   = (const float*)d_in[9];
  const float* Wb   = (const float*)d_in[10];
  const float* bb   = (const float*)d_in[11];

  int B   = in_sizes[0];
  int NNZ = in_sizes[3];
  int U   = in_sizes[6] / D;
  int I   = in_sizes[7] / D;
  int N   = U + I;
  int L   = in_sizes[9] / D;
  int nbk = (N + RPB - 1) >> RPB_SHIFT;
  int Tc  = (N + (1 << TCSH) - 1) >> TCSH;

  char* wsp = (char*)d_ws;
  auto alloc = [&](size_t bytes) -> char* {
    char* p = wsp; wsp += (bytes + 255) & ~(size_t)255; return p;
  };
  size_t side_bytes = (size_t)N * D * 2;
  size_t ebuf_bytes = (size_t)NNZ * 8;
  unsigned int*  sideb  = (unsigned int*)alloc(side_bytes > ebuf_bytes ? side_bytes : ebuf_bytes);
  unsigned int*  egob   = (unsigned int*)alloc((size_t)N * D * 2);     // bf16 ego, pair-packed
  unsigned short* egof8 = (unsigned short*)alloc((size_t)N * D);       // fp8-e4m3 ego, pair-packed
  int2*          ep     = (int2*) alloc((size_t)NNZ * 8);              // CSR edges (byte-off, val)
  unsigned short* Wf    = (unsigned short*)alloc((size_t)L * 256 * D * 2);
  int*           rowptr = (int*)  alloc((size_t)(N + 1) * 4);
  int*           bcnt   = (int*)  alloc((size_t)MAXB * 4);
  int*           bbase  = (int*)  alloc((size_t)(MAXB + 1) * 4);
  int*           bcur   = (int*)  alloc((size_t)MAXB * 4);
  float*         pacc   = (float*)alloc((size_t)B * 4);
  float*         nacc   = (float*)alloc((size_t)B * 4);
  float*         regs   = (float*)alloc(256);
  int2*          ebuf   = (int2*)sideb;   // staging alias (build phase only)

  hipMemsetAsync(bcnt, 0, (size_t)nbk * 4, stream);
  hipMemsetAsync(pacc, 0, (size_t)B * 4, stream);
  hipMemsetAsync(nacc, 0, (size_t)B * 4, stream);
  hipMemsetAsync(regs, 0, 4, stream);

  toq_kernel<<<(N*64 + 255) / 256, 256, 0, stream>>>(uemb, iemb, egob, egof8, U*64, N*64);
  wconv_kernel<<<(L*256*D + 255) / 256, 256, 0, stream>>>(Wg, Wb, Wf, L);

  // Bucketed CSR build (edges within a row ordered by col-tile)
  bhist_kernel<<<2048, 256, 0, stream>>>(erow, bcnt, NNZ, nbk);
  bscan_kernel<<<1, 1024, 0, stream>>>(bcnt, bbase, bcur, rowptr, nbk, NNZ, N);
  bscatter_kernel<<<(NNZ + CHUNK - 1) / CHUNK, 256, 0, stream>>>(erow, ecol, eval, bcur, ebuf, NNZ, nbk);
  fscatter_kernel<<<nbk, 256, 0, stream>>>(ebuf, bbase, ep, rowptr, Tc, N);

  // Block 0 (raw embeddings, un-normalized)
  score_kernel<<<(B + 3) / 4, 256, 0, stream>>>(egob, user, pos, neg, pacc, nacc, B, U, 0);

  int sampledN = 3 * B;
  bool use_samp = (sampledN < N);

  for (int l = 0; l < L; l++){
    if (use_samp && l == L - 1){
      // Final layer: only rows read by the loss (user | U+pos | U+neg).
      spmm_samp_kernel<<<(sampledN + 3) / 4, 256, 0, stream>>>(
          rowptr, ep, (const unsigned char*)egof8, sideb, user, pos, neg, B, U);
      transform_samp_kernel<<<(sampledN + 63) / 64, 256, 0, stream>>>(
          sideb, egob, Wf + (size_t)l * 256 * D,
          bg + (size_t)l * D, bb + (size_t)l * D, user, pos, neg, B, U);
    } else {
      spmm_kernel<<<(N + 3) / 4, 256, 0, stream>>>(rowptr, ep, (const unsigned char*)egof8, sideb, N);
      transform_kernel<<<(N + 63) / 64, 256, 0, stream>>>(
          sideb, egob, (unsigned char*)egof8, Wf + (size_t)l * 256 * D,
          bg + (size_t)l * D, bb + (size_t)l * D, N);
    }
    score_kernel<<<(B + 3) / 4, 256, 0, stream>>>(egob, user, pos, neg, pacc, nacc, B, U, 1);
  }

  reg_kernel<<<(B + 3) / 4, 256, 0, stream>>>(iemb, pos, neg, regs, B);
  final_kernel<<<1, 256, 0, stream>>>(pacc, nacc, regs, (float*)d_out, B);
}